// Round 8
// baseline (131.468 us; speedup 1.0000x reference)
//
#include <hip/hip_runtime.h>
#include <hip/hip_bf16.h>

typedef _Float16 f16x8 __attribute__((ext_vector_type(8)));
typedef _Float16 f16x4 __attribute__((ext_vector_type(4)));
typedef float f32x4 __attribute__((ext_vector_type(4)));

#define T_DIM 2048
#define H_DIM 2048
#define N_HEADS 16
#define DH 128
#define KBLK 50
#define NBLK 41
#define NEGV (-1.0e9f)
#define QSCALE 0.08838834764831845f  // 128^-0.5

__device__ __forceinline__ void gl_lds16(const void* g, void* l) {
    __builtin_amdgcn_global_load_lds(
        (const __attribute__((address_space(1))) void*)g,
        (__attribute__((address_space(3))) void*)l, 16, 0, 0);
}

// ---- fused prep: z<4 -> transpose weight fp32->fp16 (64x64 tiles, f16x4 stores);
//      z==4 -> convert x fp32->fp16 (16 elems/thread) ----
__global__ __launch_bounds__(256) void prep_kernel(const float* __restrict__ x,
                                                   const float* __restrict__ Wq,
                                                   const float* __restrict__ Wk,
                                                   const float* __restrict__ Wv,
                                                   const float* __restrict__ Wo,
                                                   _Float16* __restrict__ xb,
                                                   _Float16* __restrict__ WT,
                                                   _Float16* __restrict__ WoT) {
    int z = blockIdx.z;
    int tx = threadIdx.x, ty = threadIdx.y;  // 32 x 8
    int t = ty * 32 + tx;
    if (z == 4) {
        int flat = blockIdx.y * 32 + blockIdx.x;  // 1024 blocks
        int i0 = (flat * 256 + t) * 16;
#pragma unroll
        for (int h = 0; h < 2; h++) {
            float4 a = *(const float4*)&x[i0 + h * 8];
            float4 b = *(const float4*)&x[i0 + h * 8 + 4];
            f16x8 o = {(_Float16)a.x, (_Float16)a.y, (_Float16)a.z, (_Float16)a.w,
                       (_Float16)b.x, (_Float16)b.y, (_Float16)b.z, (_Float16)b.w};
            *(f16x8*)&xb[i0 + h * 8] = o;
        }
        return;
    }
    __shared__ float tile[64][65];
    const float* src = (z == 0) ? Wq : (z == 1) ? Wk : (z == 2) ? Wv : Wo;
    _Float16* dst = (z == 3) ? WoT : (WT + (size_t)z * T_DIM * H_DIM);
    int bx = blockIdx.x * 64, by = blockIdx.y * 64;
#pragma unroll
    for (int i = 0; i < 8; i++) {
        int row = ty + i * 8;
        tile[row][tx] = src[(size_t)(by + row) * H_DIM + bx + tx];
        tile[row][tx + 32] = src[(size_t)(by + row) * H_DIM + bx + tx + 32];
    }
    __syncthreads();
#pragma unroll
    for (int it = 0; it < 4; it++) {
        int idx = it * 256 + t;
        int r = idx >> 4, c4 = (idx & 15) * 4;
        f16x4 v = {(_Float16)tile[c4][r], (_Float16)tile[c4 + 1][r],
                   (_Float16)tile[c4 + 2][r], (_Float16)tile[c4 + 3][r]};
        *(f16x4*)&dst[(size_t)(bx + r) * H_DIM + by + c4] = v;
    }
}

// =============== QKV projection: 256x192 tile, 4-phase, grid 256 (1 block/CU) ============
// Proven ledger (r6). XCD swizzle now N-major: each XCD owns 4 bx-columns -> B slice
// (3MB) L2-resident & reused 8x; A panels flow through L3 once per XCD (64MB vs 192MB).
__global__ __launch_bounds__(512, 2) void qkv192_kernel(const _Float16* __restrict__ A,
                                                        const _Float16* __restrict__ BT,
                                                        _Float16* __restrict__ qkv) {
    const int K = 2048, NT = 32;
    __shared__ _Float16 smem[57344];  // 112KB: A dbuf 2x16384 | B dbuf 2x12288
    _Float16* sA0 = smem;
    _Float16* sA1 = smem + 16384;
    _Float16* sB0 = smem + 32768;
    _Float16* sB1 = smem + 45056;

    int tid = threadIdx.x;
    int lane = tid & 63, wave = tid >> 6;
    int wm = wave >> 2, wn = wave & 3;
    int cb = lane & 15, hi = lane >> 4;

    int bid = blockIdx.x;
    int bx = (bid & 7) * 4 + ((bid >> 3) & 3);  // XCD owns 4 N-columns
    int by = bid >> 5;
    int bm = by * 256, bn = bx * 192;

    f32x4 acc[8][3];
#pragma unroll
    for (int m = 0; m < 8; m++)
#pragma unroll
        for (int n = 0; n < 3; n++) acc[m][n] = (f32x4){0.f, 0.f, 0.f, 0.f};

    int rp = tid >> 3, cc = tid & 7;
    int scol = ((cc ^ (rp & 7)) << 3);  // pre-swizzled source col (f16 units)

    auto stageA = [&](int t, int u) {
        int buf = t & 1;
        gl_lds16(A + (size_t)(bm + u * 64 + rp) * K + (t << 6) + scol,
                 (buf ? sA1 : sA0) + u * 4096 + tid * 8);
    };
    auto stageB = [&](int t, int u) {
        int buf = t & 1;
        gl_lds16(BT + (size_t)(bn + u * 64 + rp) * K + (t << 6) + scol,
                 (buf ? sB1 : sB0) + u * 4096 + tid * 8);
    };

    f16x8 a_lo[4][2], a_hi[4][2], b01[2][2], b2[2];

    stageA(0, 0); stageA(0, 1); stageA(0, 2); stageA(0, 3);
    stageB(0, 0); stageB(0, 1); stageB(0, 2);
    stageA(1, 0); stageA(1, 1); stageA(1, 2); stageA(1, 3);
    asm volatile("s_waitcnt vmcnt(4)" ::: "memory");
    __builtin_amdgcn_s_barrier();

    for (int t = 0; t < NT; t++) {
        int buf = t & 1;
        const char* bA = (const char*)(buf ? sA1 : sA0);
        const char* bB = (const char*)(buf ? sB1 : sB0);
        // ph0: read a_lo + b01; stage B0,B1(t+1); MFMA a_lo x b01
#pragma unroll
        for (int mf = 0; mf < 4; mf++) {
            int ra = wm * 128 + mf * 16 + cb;
#pragma unroll
            for (int ks = 0; ks < 2; ks++)
                a_lo[mf][ks] = *(const f16x8*)(bA + (ra << 7) +
                                               ((ks * 64 + hi * 16) ^ ((ra & 7) << 4)));
        }
#pragma unroll
        for (int nf = 0; nf < 2; nf++) {
            int rb = wn * 48 + nf * 16 + cb;
#pragma unroll
            for (int ks = 0; ks < 2; ks++)
                b01[nf][ks] = *(const f16x8*)(bB + (rb << 7) +
                                              ((ks * 64 + hi * 16) ^ ((rb & 7) << 4)));
        }
        if (t + 1 < NT) { stageB(t + 1, 0); stageB(t + 1, 1); }
        __builtin_amdgcn_s_barrier();
        asm volatile("s_waitcnt lgkmcnt(0)" ::: "memory");
        __builtin_amdgcn_s_setprio(1);
#pragma unroll
        for (int mf = 0; mf < 4; mf++)
#pragma unroll
            for (int nf = 0; nf < 2; nf++)
#pragma unroll
                for (int ks = 0; ks < 2; ks++)
                    acc[mf][nf] = __builtin_amdgcn_mfma_f32_16x16x32_f16(a_lo[mf][ks], b01[nf][ks], acc[mf][nf], 0, 0, 0);
        __builtin_amdgcn_s_setprio(0);
        __builtin_amdgcn_s_barrier();

        // ph1: read a_hi + b2; stage B2(t+1); MFMA a_hi x b2
#pragma unroll
        for (int mf = 0; mf < 4; mf++) {
            int ra = wm * 128 + 64 + mf * 16 + cb;
#pragma unroll
            for (int ks = 0; ks < 2; ks++)
                a_hi[mf][ks] = *(const f16x8*)(bA + (ra << 7) +
                                               ((ks * 64 + hi * 16) ^ ((ra & 7) << 4)));
        }
        {
            int rb = wn * 48 + 32 + cb;
#pragma unroll
            for (int ks = 0; ks < 2; ks++)
                b2[ks] = *(const f16x8*)(bB + (rb << 7) +
                                         ((ks * 64 + hi * 16) ^ ((rb & 7) << 4)));
        }
        if (t + 1 < NT) stageB(t + 1, 2);
        __builtin_amdgcn_s_barrier();
        asm volatile("s_waitcnt lgkmcnt(0)" ::: "memory");
        __builtin_amdgcn_s_setprio(1);
#pragma unroll
        for (int mf = 0; mf < 4; mf++)
#pragma unroll
            for (int ks = 0; ks < 2; ks++)
                acc[4 + mf][2] = __builtin_amdgcn_mfma_f32_16x16x32_f16(a_hi[mf][ks], b2[ks], acc[4 + mf][2], 0, 0, 0);
        __builtin_amdgcn_s_setprio(0);
        __builtin_amdgcn_s_barrier();

        // ph2: stage A0,A1(t+2); MFMA a_lo x b2
        if (t + 2 < NT) { stageA(t + 2, 0); stageA(t + 2, 1); }
        __builtin_amdgcn_s_barrier();
        __builtin_amdgcn_s_setprio(1);
#pragma unroll
        for (int mf = 0; mf < 4; mf++)
#pragma unroll
            for (int ks = 0; ks < 2; ks++)
                acc[mf][2] = __builtin_amdgcn_mfma_f32_16x16x32_f16(a_lo[mf][ks], b2[ks], acc[mf][2], 0, 0, 0);
        __builtin_amdgcn_s_setprio(0);
        __builtin_amdgcn_s_barrier();

        // ph3: stage A2,A3(t+2); vmcnt confirms tile t+1; MFMA a_hi x b01
        if (t + 2 < NT) { stageA(t + 2, 2); stageA(t + 2, 3); }
        if (t < NT - 2)
            asm volatile("s_waitcnt vmcnt(4)" ::: "memory");
        else if (t == NT - 2)
            asm volatile("s_waitcnt vmcnt(0)" ::: "memory");
        __builtin_amdgcn_s_barrier();
        __builtin_amdgcn_s_setprio(1);
#pragma unroll
        for (int mf = 0; mf < 4; mf++)
#pragma unroll
            for (int nf = 0; nf < 2; nf++)
#pragma unroll
                for (int ks = 0; ks < 2; ks++)
                    acc[4 + mf][nf] = __builtin_amdgcn_mfma_f32_16x16x32_f16(a_hi[mf][ks], b01[nf][ks], acc[4 + mf][nf], 0, 0, 0);
        __builtin_amdgcn_s_setprio(0);
        __builtin_amdgcn_s_barrier();
    }

    // epilogue: LDS repack (two 128-row passes, [128][200]) -> uint4 stores
#pragma unroll
    for (int p = 0; p < 2; p++) {
        if (p) __builtin_amdgcn_s_barrier();
        if (wm == p) {
#pragma unroll
            for (int mf = 0; mf < 8; mf++)
#pragma unroll
                for (int nf = 0; nf < 3; nf++) {
                    int col = wn * 48 + nf * 16 + cb;
                    float sc = ((bn + col) >> 11) == 0 ? QSCALE : 1.0f;
#pragma unroll
                    for (int r = 0; r < 4; r++) {
                        int row = mf * 16 + hi * 4 + r;
                        smem[row * 200 + col] = (_Float16)(acc[mf][nf][r] * sc);
                    }
                }
        }
        __builtin_amdgcn_s_barrier();
#pragma unroll
        for (int it = 0; it < 6; it++) {
            int c = it * 512 + tid;  // 3072 chunks = 128 rows x 24
            int row = c / 24, col8 = c - row * 24;
            int gm = bm + p * 128 + row;
            int gn = bn + col8 * 8;
            int tensor = gn >> 11;
            int ef = gn & 2047;
            int e = ef >> 7, f0 = ef & 127;
            uint4 v = *(const uint4*)&smem[row * 200 + col8 * 8];
            *(uint4*)(qkv + (size_t)tensor * (T_DIM * H_DIM) + (size_t)e * (T_DIM * DH) +
                      (size_t)gm * DH + f0) = v;
        }
    }
}

// =============== out-proj: 256x256 8-phase, split-K=4, fp16 partials =================
// Proven ledger (r6). XCD swizzle: bx = bid&7 -> B panel (1MB) L2-resident, reused 32x.
__global__ __launch_bounds__(512, 2) void oproj_kernel(const _Float16* __restrict__ A,
                                                       const _Float16* __restrict__ BT,
                                                       _Float16* __restrict__ part) {
    const int K = 2048, NT = 8;
    __shared__ _Float16 smem[65536];  // 128KB
    _Float16* sA0 = smem;
    _Float16* sA1 = smem + 16384;
    _Float16* sB0 = smem + 32768;
    _Float16* sB1 = smem + 49152;

    int tid = threadIdx.x;
    int lane = tid & 63, wave = tid >> 6;
    int wm = wave >> 2, wn = wave & 3;
    int cb = lane & 15, hi = lane >> 4;

    int bid = blockIdx.x;
    int bx = bid & 7;            // XCD owns one N-column of tiles
    int rest = bid >> 3;
    int by = rest & 7, s = rest >> 3;
    int bm = by * 256, bn = bx * 256;
    int kbase = s * 512;

    f32x4 acc[8][4];
#pragma unroll
    for (int m = 0; m < 8; m++)
#pragma unroll
        for (int n = 0; n < 4; n++) acc[m][n] = (f32x4){0.f, 0.f, 0.f, 0.f};

    auto stageP = [&](int t, int p) {
        int buf = t & 1, k0 = kbase + (t << 6);
        const _Float16* src = (p < 2) ? A + (size_t)(bm + ((p & 1) << 7)) * K + k0
                                      : BT + (size_t)(bn + ((p & 1) << 7)) * K + k0;
        _Float16* dst = ((p < 2) ? (buf ? sA1 : sA0) : (buf ? sB1 : sB0)) + ((p & 1) << 13);
#pragma unroll
        for (int l = 0; l < 2; l++) {
            int c = l * 512 + tid;
            int rp = c >> 3, cc = c & 7;
            int col = (cc ^ (rp & 7)) << 3;
            gl_lds16(src + (size_t)rp * K + col, dst + c * 8);
        }
    };

    f16x8 a_lo[4][2], a_hi[4][2], b_lo[2][2], b_hi[2][2];

    stageP(0, 0); stageP(0, 1); stageP(0, 2); stageP(0, 3);
    stageP(1, 0); stageP(1, 1);
    asm volatile("s_waitcnt vmcnt(4)" ::: "memory");
    __builtin_amdgcn_s_barrier();

    for (int t = 0; t < NT; t++) {
        int buf = t & 1;
        const char* bA = (const char*)(buf ? sA1 : sA0);
        const char* bB = (const char*)(buf ? sB1 : sB0);
        // ph0
#pragma unroll
        for (int m = 0; m < 4; m++) {
            int ra = wm * 128 + m * 16 + cb;
#pragma unroll
            for (int ks = 0; ks < 2; ks++)
                a_lo[m][ks] = *(const f16x8*)(bA + (ra << 7) +
                                              ((ks * 64 + hi * 16) ^ ((ra & 7) << 4)));
        }
#pragma unroll
        for (int n = 0; n < 2; n++) {
            int rb = wn * 64 + n * 16 + cb;
#pragma unroll
            for (int ks = 0; ks < 2; ks++)
                b_lo[n][ks] = *(const f16x8*)(bB + (rb << 7) +
                                              ((ks * 64 + hi * 16) ^ ((rb & 7) << 4)));
        }
        if (t + 1 < NT) stageP(t + 1, 2);
        __builtin_amdgcn_s_barrier();
        asm volatile("s_waitcnt lgkmcnt(0)" ::: "memory");
        __builtin_amdgcn_s_setprio(1);
#pragma unroll
        for (int m = 0; m < 4; m++)
#pragma unroll
            for (int n = 0; n < 2; n++)
#pragma unroll
                for (int ks = 0; ks < 2; ks++)
                    acc[m][n] = __builtin_amdgcn_mfma_f32_16x16x32_f16(a_lo[m][ks], b_lo[n][ks], acc[m][n], 0, 0, 0);
        __builtin_amdgcn_s_setprio(0);
        __builtin_amdgcn_s_barrier();

        // ph1
#pragma unroll
        for (int m = 0; m < 4; m++) {
            int ra = wm * 128 + 64 + m * 16 + cb;
#pragma unroll
            for (int ks = 0; ks < 2; ks++)
                a_hi[m][ks] = *(const f16x8*)(bA + (ra << 7) +
                                              ((ks * 64 + hi * 16) ^ ((ra & 7) << 4)));
        }
#pragma unroll
        for (int n = 0; n < 2; n++) {
            int rb = wn * 64 + 32 + n * 16 + cb;
#pragma unroll
            for (int ks = 0; ks < 2; ks++)
                b_hi[n][ks] = *(const f16x8*)(bB + (rb << 7) +
                                              ((ks * 64 + hi * 16) ^ ((rb & 7) << 4)));
        }
        if (t + 1 < NT) stageP(t + 1, 3);
        __builtin_amdgcn_s_barrier();
        asm volatile("s_waitcnt lgkmcnt(0)" ::: "memory");
        __builtin_amdgcn_s_setprio(1);
#pragma unroll
        for (int m = 0; m < 4; m++)
#pragma unroll
            for (int n = 0; n < 2; n++)
#pragma unroll
                for (int ks = 0; ks < 2; ks++)
                    acc[4 + m][2 + n] = __builtin_amdgcn_mfma_f32_16x16x32_f16(a_hi[m][ks], b_hi[n][ks], acc[4 + m][2 + n], 0, 0, 0);
        __builtin_amdgcn_s_setprio(0);
        __builtin_amdgcn_s_barrier();

        // ph2
        if (t + 2 < NT) stageP(t + 2, 0);
        __builtin_amdgcn_s_barrier();
        __builtin_amdgcn_s_setprio(1);
#pragma unroll
        for (int m = 0; m < 4; m++)
#pragma unroll
            for (int n = 0; n < 2; n++)
#pragma unroll
                for (int ks = 0; ks < 2; ks++)
                    acc[m][2 + n] = __builtin_amdgcn_mfma_f32_16x16x32_f16(a_lo[m][ks], b_hi[n][ks], acc[m][2 + n], 0, 0, 0);
        __builtin_amdgcn_s_setprio(0);
        __builtin_amdgcn_s_barrier();

        // ph3
        if (t + 2 < NT) stageP(t + 2, 1);
        if (t < NT - 2)
            asm volatile("s_waitcnt vmcnt(4)" ::: "memory");
        else if (t == NT - 2)
            asm volatile("s_waitcnt vmcnt(0)" ::: "memory");
        __builtin_amdgcn_s_barrier();
        __builtin_amdgcn_s_setprio(1);
#pragma unroll
        for (int m = 0; m < 4; m++)
#pragma unroll
            for (int n = 0; n < 2; n++)
#pragma unroll
                for (int ks = 0; ks < 2; ks++)
                    acc[4 + m][n] = __builtin_amdgcn_mfma_f32_16x16x32_f16(a_hi[m][ks], b_lo[n][ks], acc[4 + m][n], 0, 0, 0);
        __builtin_amdgcn_s_setprio(0);
        __builtin_amdgcn_s_barrier();
    }

    // epilogue: LDS repack -> coalesced partial stores
    _Float16* pb = part + (size_t)s * T_DIM * H_DIM;
#pragma unroll
    for (int p = 0; p < 2; p++) {
        if (p) __builtin_amdgcn_s_barrier();
        if (wm == p) {
#pragma unroll
            for (int m = 0; m < 8; m++)
#pragma unroll
                for (int n = 0; n < 4; n++) {
                    int col = wn * 64 + ((n & 1) * 16) + ((n >> 1) * 32) + cb;
#pragma unroll
                    for (int r = 0; r < 4; r++) {
                        int row = ((m & 3) * 16) + ((m >> 2) * 64) + hi * 4 + r;
                        smem[row * 264 + col] = (_Float16)acc[m][n][r];
                    }
                }
        }
        __builtin_amdgcn_s_barrier();
#pragma unroll
        for (int it = 0; it < 8; it++) {
            int c = it * 512 + tid;  // 4096 chunks = 128 rows x 32
            int row = c >> 5, col8 = c & 31;
            int gm = bm + p * 128 + row;
            int gn = bn + col8 * 8;
            uint4 v = *(const uint4*)&smem[row * 264 + col8 * 8];
            *(uint4*)&pb[(size_t)gm * H_DIM + gn] = v;
        }
    }
}

// ---------------- reduce 4 fp16 partials -> fp32 out ----------------
__global__ __launch_bounds__(256) void reduce4_kernel(const _Float16* __restrict__ part,
                                                      float* __restrict__ out) {
    const size_t S = (size_t)T_DIM * H_DIM;
    int i = (blockIdx.x * 256 + threadIdx.x) * 8;
    f16x8 p0 = *(const f16x8*)&part[i];
    f16x8 p1 = *(const f16x8*)&part[S + i];
    f16x8 p2 = *(const f16x8*)&part[2 * S + i];
    f16x8 p3 = *(const f16x8*)&part[3 * S + i];
#pragma unroll
    for (int j = 0; j < 8; j++)
        out[i + j] = (float)p0[j] + (float)p1[j] + (float)p2[j] + (float)p3[j];
}

// ---------------- per-(block,head) attention ----------------
// NEW: bias tile staged to LDS via coalesced loads (was 16 scattered 4B loads/thread).
__global__ __launch_bounds__(256) void attn_kernel(const _Float16* __restrict__ qkvb,
                                                   const float* __restrict__ bias,
                                                   const float* __restrict__ mask,
                                                   _Float16* __restrict__ aout) {
    int bid = blockIdx.x;
    int n = bid >> 4, e = bid & 15;
    int t0 = n * KBLK;
    int valid = (T_DIM - t0 < KBLK) ? (T_DIM - t0) : KBLK;

    __shared__ _Float16 Qs[64 * 136];
    __shared__ _Float16 Ks[64 * 136];
    __shared__ _Float16 VTs[128 * 72];
    __shared__ _Float16 Ps[64 * 72];
    __shared__ float Bs[50 * 64];
    __shared__ float maskv[64];

    int tid = threadIdx.x;
    int lane = tid & 63, wave = tid >> 6;
    const _Float16* qp = qkvb + (size_t)e * (T_DIM * DH);
    const _Float16* kp = qkvb + (size_t)(T_DIM * H_DIM) + (size_t)e * (T_DIM * DH);
    const _Float16* vp = qkvb + (size_t)2 * (T_DIM * H_DIM) + (size_t)e * (T_DIM * DH);

#pragma unroll
    for (int i = 0; i < 4; i++) {
        int c = tid + i * 256;
        int r = c >> 4, c8 = c & 15;
        uint4 z = {0u, 0u, 0u, 0u};
        uint4 vq = z, vk = z;
        if (r < valid) {
            vq = *(const uint4*)&qp[(size_t)(t0 + r) * DH + c8 * 8];
            vk = *(const uint4*)&kp[(size_t)(t0 + r) * DH + c8 * 8];
        }
        *(uint4*)&Qs[r * 136 + c8 * 8] = vq;
        *(uint4*)&Ks[r * 136 + c8 * 8] = vk;
    }
#pragma unroll
    for (int i = 0; i < 4; i++) {
        int c = tid + i * 256;
        int r = c & 63;
        int f0 = (c >> 6) * 8;
        uint4 v = {0u, 0u, 0u, 0u};
        if (r < valid) v = *(const uint4*)&vp[(size_t)(t0 + r) * DH + f0];
        _Float16 tmp[8];
        *(uint4*)tmp = v;
#pragma unroll
        for (int j = 0; j < 8; j++) VTs[(f0 + j) * 72 + r] = tmp[j];
    }
    // bias tile: Bs[r][c] = bias[e][t0+r][t0+c] (zeros outside valid range)
    {
        const float* bp = bias + ((size_t)e * T_DIM + t0) * T_DIM + t0;
        int klim = T_DIM - t0;
        if (klim > KBLK) klim = KBLK;
#pragma unroll
        for (int i = 0; i < 13; i++) {
            int idx = i * 256 + tid;
            int r = idx >> 6, c = idx & 63;
            if (r < KBLK) {
                float v = (r < valid && c < klim) ? bp[(size_t)r * T_DIM + c] : 0.f;
                Bs[r * 64 + c] = v;
            }
        }
    }
    if (tid < 64) maskv[tid] = (tid < valid) ? mask[t0 + tid] : NEGV;
    __syncthreads();

    int qr0 = wave * 16;
    int cb = lane & 15, hi = lane >> 4;

    f16x8 aq[4];
#pragma unroll
    for (int ks = 0; ks < 4; ks++)
        aq[ks] = *(const f16x8*)&Qs[(qr0 + cb) * 136 + ks * 32 + hi * 8];
    f32x4 s[4];
#pragma unroll
    for (int kt = 0; kt < 4; kt++) s[kt] = (f32x4){0.f, 0.f, 0.f, 0.f};
#pragma unroll
    for (int kt = 0; kt < 4; kt++)
#pragma unroll
        for (int ks = 0; ks < 4; ks++) {
            f16x8 bk = *(const f16x8*)&Ks[(kt * 16 + cb) * 136 + ks * 32 + hi * 8];
            s[kt] = __builtin_amdgcn_mfma_f32_16x16x32_f16(aq[ks], bk, s[kt], 0, 0, 0);
        }

#pragma unroll
    for (int r = 0; r < 4; r++) {
        int rl = qr0 + hi * 4 + r;
        float mq = maskv[rl];
        float lg[4];
        float mx = -3.4e38f;
#pragma unroll
        for (int kt = 0; kt < 4; kt++) {
            int cl = kt * 16 + cb;
            float bg = (rl < KBLK && cl < KBLK) ? Bs[rl * 64 + cl] : 0.f;
            float pr = mq * maskv[cl];
            float v = s[kt][r] + bg + (pr > 0.f ? 0.f : NEGV);
            lg[kt] = v;
            mx = fmaxf(mx, v);
        }
#pragma unroll
        for (int off = 8; off; off >>= 1) mx = fmaxf(mx, __shfl_xor(mx, off));
        float sum = 0.f;
#pragma unroll
        for (int kt = 0; kt < 4; kt++) {
            float pe = __expf(lg[kt] - mx);
            lg[kt] = pe;
            sum += pe;
        }
#pragma unroll
        for (int off = 8; off; off >>= 1) sum += __shfl_xor(sum, off);
        float inv = 1.f / sum;
#pragma unroll
        for (int kt = 0; kt < 4; kt++)
            Ps[rl * 72 + kt * 16 + cb] = (_Float16)(lg[kt] * inv);
    }
    __syncthreads();

    f16x8 pa[2];
#pragma unroll
    for (int ks = 0; ks < 2; ks++)
        pa[ks] = *(const f16x8*)&Ps[(qr0 + cb) * 72 + ks * 32 + hi * 8];
#pragma unroll
    for (int ft = 0; ft < 8; ft++) {
        f32x4 o = (f32x4){0.f, 0.f, 0.f, 0.f};
#pragma unroll
        for (int ks = 0; ks < 2; ks++) {
            f16x8 bv = *(const f16x8*)&VTs[(ft * 16 + cb) * 72 + ks * 32 + hi * 8];
            o = __builtin_amdgcn_mfma_f32_16x16x32_f16(pa[ks], bv, o, 0, 0, 0);
        }
#pragma unroll
        for (int r = 0; r < 4; r++) {
            int rl = qr0 + hi * 4 + r;
            if (rl < valid)
                aout[(size_t)(t0 + rl) * H_DIM + e * DH + ft * 16 + cb] = (_Float16)o[r];
        }
    }
}

extern "C" void kernel_launch(void* const* d_in, const int* in_sizes, int n_in,
                              void* d_out, int out_size, void* d_ws, size_t ws_size,
                              hipStream_t stream) {
    const float* x    = (const float*)d_in[0];
    const float* mask = (const float*)d_in[1];
    const float* bias = (const float*)d_in[2];
    const float* Wq   = (const float*)d_in[3];
    const float* Wk   = (const float*)d_in[4];
    const float* Wv   = (const float*)d_in[5];
    const float* Wo   = (const float*)d_in[6];
    float* out = (float*)d_out;

    // ws layout (f16): xb[4M] | WT[12M] | WoT[4M] | qkv[12M] | aout[4M] | part[16M] = 104MB
    _Float16* xb   = (_Float16*)d_ws;
    _Float16* WT   = xb + (size_t)T_DIM * H_DIM;
    _Float16* WoT  = WT + (size_t)3 * T_DIM * H_DIM;
    _Float16* qkvb = WoT + (size_t)T_DIM * H_DIM;
    _Float16* aout = qkvb + (size_t)3 * T_DIM * H_DIM;
    _Float16* part = aout + (size_t)T_DIM * H_DIM;

    prep_kernel<<<dim3(32, 32, 5), dim3(32, 8), 0, stream>>>(x, Wq, Wk, Wv, Wo, xb, WT, WoT);

    qkv192_kernel<<<256, 512, 0, stream>>>(xb, WT, qkvb);

    attn_kernel<<<NBLK * N_HEADS, 256, 0, stream>>>(qkvb, bias, mask, aout);

    oproj_kernel<<<256, 512, 0, stream>>>(aout, WoT, part);
    reduce4_kernel<<<(T_DIM * H_DIM) / (256 * 8), 256, 0, stream>>>(part, out);
}

// Round 9
// 119.405 us; speedup vs baseline: 1.1010x; 1.1010x over previous
//
#include <hip/hip_runtime.h>
#include <hip/hip_bf16.h>

typedef _Float16 f16x8 __attribute__((ext_vector_type(8)));
typedef float f32x4 __attribute__((ext_vector_type(4)));

#define T_DIM 2048
#define H_DIM 2048
#define N_HEADS 16
#define DH 128
#define KBLK 50
#define NBLK 41
#define NEGV (-1.0e9f)
#define QSCALE 0.08838834764831845f  // 128^-0.5

__device__ __forceinline__ void gl_lds16(const void* g, void* l) {
    __builtin_amdgcn_global_load_lds(
        (const __attribute__((address_space(1))) void*)g,
        (__attribute__((address_space(3))) void*)l, 16, 0, 0);
}

// ---- fused prep (round-7 version): z<4 weight transpose fp32->fp16; z==4 x convert ----
__global__ __launch_bounds__(256) void prep_kernel(const float* __restrict__ x,
                                                   const float* __restrict__ Wq,
                                                   const float* __restrict__ Wk,
                                                   const float* __restrict__ Wv,
                                                   const float* __restrict__ Wo,
                                                   _Float16* __restrict__ xb,
                                                   _Float16* __restrict__ WT,
                                                   _Float16* __restrict__ WoT) {
    __shared__ float tile[32][33];
    int z = blockIdx.z;
    int tx = threadIdx.x, ty = threadIdx.y;  // 32 x 8
    if (z == 4) {
        if (blockIdx.y >= 32) return;
        int flat = blockIdx.y * 64 + blockIdx.x;
        int i = (flat * 256 + ty * 32 + tx) * 8;
        float4 a = *(const float4*)&x[i];
        float4 b = *(const float4*)&x[i + 4];
        f16x8 o = {(_Float16)a.x, (_Float16)a.y, (_Float16)a.z, (_Float16)a.w,
                   (_Float16)b.x, (_Float16)b.y, (_Float16)b.z, (_Float16)b.w};
        *(f16x8*)&xb[i] = o;
        return;
    }
    const float* src = (z == 0) ? Wq : (z == 1) ? Wk : (z == 2) ? Wv : Wo;
    _Float16* dst = (z == 3) ? WoT : (WT + (size_t)z * T_DIM * H_DIM);
    int bx = blockIdx.x * 32, by = blockIdx.y * 32;
#pragma unroll
    for (int i = 0; i < 4; i++)
        tile[ty + i * 8][tx] = src[(size_t)(by + ty + i * 8) * H_DIM + bx + tx];
    __syncthreads();
#pragma unroll
    for (int i = 0; i < 4; i++)
        dst[(size_t)(bx + ty + i * 8) * H_DIM + by + tx] = (_Float16)tile[tx][ty + i * 8];
}

// =============== QKV projection: 256x192 tile, 4-phase, grid 256 (round-7, unchanged) ====
__global__ __launch_bounds__(512, 2) void qkv192_kernel(const _Float16* __restrict__ A,
                                                        const _Float16* __restrict__ BT,
                                                        _Float16* __restrict__ qkv) {
    const int K = 2048, NT = 32;
    __shared__ _Float16 smem[57344];  // 112KB: A dbuf 2x16384 | B dbuf 2x12288
    _Float16* sA0 = smem;
    _Float16* sA1 = smem + 16384;
    _Float16* sB0 = smem + 32768;
    _Float16* sB1 = smem + 45056;

    int tid = threadIdx.x;
    int lane = tid & 63, wave = tid >> 6;
    int wm = wave >> 2, wn = wave & 3;
    int cb = lane & 15, hi = lane >> 4;

    int bid = blockIdx.x;
    int swz = (bid & 7) * 32 + (bid >> 3);
    int by = swz >> 5, bx = swz & 31;
    int bm = by * 256, bn = bx * 192;

    f32x4 acc[8][3];
#pragma unroll
    for (int m = 0; m < 8; m++)
#pragma unroll
        for (int n = 0; n < 3; n++) acc[m][n] = (f32x4){0.f, 0.f, 0.f, 0.f};

    int rp = tid >> 3, cc = tid & 7;
    int scol = ((cc ^ (rp & 7)) << 3);  // pre-swizzled source col (f16 units)

    auto stageA = [&](int t, int u) {
        int buf = t & 1;
        gl_lds16(A + (size_t)(bm + u * 64 + rp) * K + (t << 6) + scol,
                 (buf ? sA1 : sA0) + u * 4096 + tid * 8);
    };
    auto stageB = [&](int t, int u) {
        int buf = t & 1;
        gl_lds16(BT + (size_t)(bn + u * 64 + rp) * K + (t << 6) + scol,
                 (buf ? sB1 : sB0) + u * 4096 + tid * 8);
    };

    f16x8 a_lo[4][2], a_hi[4][2], b01[2][2], b2[2];

    stageA(0, 0); stageA(0, 1); stageA(0, 2); stageA(0, 3);
    stageB(0, 0); stageB(0, 1); stageB(0, 2);
    stageA(1, 0); stageA(1, 1); stageA(1, 2); stageA(1, 3);
    asm volatile("s_waitcnt vmcnt(4)" ::: "memory");
    __builtin_amdgcn_s_barrier();

    for (int t = 0; t < NT; t++) {
        int buf = t & 1;
        const char* bA = (const char*)(buf ? sA1 : sA0);
        const char* bB = (const char*)(buf ? sB1 : sB0);
        // ph0: read a_lo + b01; stage B0,B1(t+1); MFMA a_lo x b01
#pragma unroll
        for (int mf = 0; mf < 4; mf++) {
            int ra = wm * 128 + mf * 16 + cb;
#pragma unroll
            for (int ks = 0; ks < 2; ks++)
                a_lo[mf][ks] = *(const f16x8*)(bA + (ra << 7) +
                                               ((ks * 64 + hi * 16) ^ ((ra & 7) << 4)));
        }
#pragma unroll
        for (int nf = 0; nf < 2; nf++) {
            int rb = wn * 48 + nf * 16 + cb;
#pragma unroll
            for (int ks = 0; ks < 2; ks++)
                b01[nf][ks] = *(const f16x8*)(bB + (rb << 7) +
                                              ((ks * 64 + hi * 16) ^ ((rb & 7) << 4)));
        }
        if (t + 1 < NT) { stageB(t + 1, 0); stageB(t + 1, 1); }
        __builtin_amdgcn_s_barrier();
        asm volatile("s_waitcnt lgkmcnt(0)" ::: "memory");
        __builtin_amdgcn_s_setprio(1);
#pragma unroll
        for (int mf = 0; mf < 4; mf++)
#pragma unroll
            for (int nf = 0; nf < 2; nf++)
#pragma unroll
                for (int ks = 0; ks < 2; ks++)
                    acc[mf][nf] = __builtin_amdgcn_mfma_f32_16x16x32_f16(a_lo[mf][ks], b01[nf][ks], acc[mf][nf], 0, 0, 0);
        __builtin_amdgcn_s_setprio(0);
        __builtin_amdgcn_s_barrier();

        // ph1: read a_hi + b2; stage B2(t+1); MFMA a_hi x b2
#pragma unroll
        for (int mf = 0; mf < 4; mf++) {
            int ra = wm * 128 + 64 + mf * 16 + cb;
#pragma unroll
            for (int ks = 0; ks < 2; ks++)
                a_hi[mf][ks] = *(const f16x8*)(bA + (ra << 7) +
                                               ((ks * 64 + hi * 16) ^ ((ra & 7) << 4)));
        }
        {
            int rb = wn * 48 + 32 + cb;
#pragma unroll
            for (int ks = 0; ks < 2; ks++)
                b2[ks] = *(const f16x8*)(bB + (rb << 7) +
                                         ((ks * 64 + hi * 16) ^ ((rb & 7) << 4)));
        }
        if (t + 1 < NT) stageB(t + 1, 2);
        __builtin_amdgcn_s_barrier();
        asm volatile("s_waitcnt lgkmcnt(0)" ::: "memory");
        __builtin_amdgcn_s_setprio(1);
#pragma unroll
        for (int mf = 0; mf < 4; mf++)
#pragma unroll
            for (int ks = 0; ks < 2; ks++)
                acc[4 + mf][2] = __builtin_amdgcn_mfma_f32_16x16x32_f16(a_hi[mf][ks], b2[ks], acc[4 + mf][2], 0, 0, 0);
        __builtin_amdgcn_s_setprio(0);
        __builtin_amdgcn_s_barrier();

        // ph2: stage A0,A1(t+2); MFMA a_lo x b2
        if (t + 2 < NT) { stageA(t + 2, 0); stageA(t + 2, 1); }
        __builtin_amdgcn_s_barrier();
        __builtin_amdgcn_s_setprio(1);
#pragma unroll
        for (int mf = 0; mf < 4; mf++)
#pragma unroll
            for (int ks = 0; ks < 2; ks++)
                acc[mf][2] = __builtin_amdgcn_mfma_f32_16x16x32_f16(a_lo[mf][ks], b2[ks], acc[mf][2], 0, 0, 0);
        __builtin_amdgcn_s_setprio(0);
        __builtin_amdgcn_s_barrier();

        // ph3: stage A2,A3(t+2); vmcnt confirms tile t+1; MFMA a_hi x b01
        if (t + 2 < NT) { stageA(t + 2, 2); stageA(t + 2, 3); }
        if (t < NT - 2)
            asm volatile("s_waitcnt vmcnt(4)" ::: "memory");
        else if (t == NT - 2)
            asm volatile("s_waitcnt vmcnt(0)" ::: "memory");
        __builtin_amdgcn_s_barrier();
        __builtin_amdgcn_s_setprio(1);
#pragma unroll
        for (int mf = 0; mf < 4; mf++)
#pragma unroll
            for (int nf = 0; nf < 2; nf++)
#pragma unroll
                for (int ks = 0; ks < 2; ks++)
                    acc[4 + mf][nf] = __builtin_amdgcn_mfma_f32_16x16x32_f16(a_hi[mf][ks], b01[nf][ks], acc[4 + mf][nf], 0, 0, 0);
        __builtin_amdgcn_s_setprio(0);
        __builtin_amdgcn_s_barrier();
    }

    // epilogue: LDS repack (two 128-row passes, [128][200]) -> uint4 stores
#pragma unroll
    for (int p = 0; p < 2; p++) {
        if (p) __builtin_amdgcn_s_barrier();
        if (wm == p) {
#pragma unroll
            for (int mf = 0; mf < 8; mf++)
#pragma unroll
                for (int nf = 0; nf < 3; nf++) {
                    int col = wn * 48 + nf * 16 + cb;
                    float sc = ((bn + col) >> 11) == 0 ? QSCALE : 1.0f;
#pragma unroll
                    for (int r = 0; r < 4; r++) {
                        int row = mf * 16 + hi * 4 + r;
                        smem[row * 200 + col] = (_Float16)(acc[mf][nf][r] * sc);
                    }
                }
        }
        __builtin_amdgcn_s_barrier();
#pragma unroll
        for (int it = 0; it < 6; it++) {
            int c = it * 512 + tid;  // 3072 chunks = 128 rows x 24
            int row = c / 24, col8 = c - row * 24;
            int gm = bm + p * 128 + row;
            int gn = bn + col8 * 8;
            int tensor = gn >> 11;
            int ef = gn & 2047;
            int e = ef >> 7, f0 = ef & 127;
            uint4 v = *(const uint4*)&smem[row * 200 + col8 * 8];
            *(uint4*)(qkv + (size_t)tensor * (T_DIM * H_DIM) + (size_t)e * (T_DIM * DH) +
                      (size_t)gm * DH + f0) = v;
        }
    }
}

// =============== out-proj: 128x128 tile, full K, fp32 out, grid 256 (1/CU) ===============
// Triple-buffered (3x32KB LDS), 2 phases/K-tile, counted vmcnt. Ledger:
//  - units A0,A1(t+2) staged at (t,ph0); B0,B1(t+2) at (t,ph1) -> buf (t+2)%3, whose
//    last readers (iter t-1) drained lgkmcnt(0) before their ph1 MFMA + barrier.
//  - vmcnt(4) at (t,ph1): outstanding = 4 units of t+1 + 4 of t+2 -> oldest 4 (t+1)
//    landed; barrier makes it block-wide. Tail: vmcnt(0) at t=NT-2, no wait at NT-1.
__global__ __launch_bounds__(512, 1) void oproj_kernel(const _Float16* __restrict__ A,
                                                       const _Float16* __restrict__ BT,
                                                       float* __restrict__ out) {
    const int K = 2048, NT = 32;
    __shared__ _Float16 smem[49152];  // 96KB: 3 bufs x (A 8192 f16 | B 8192 f16)

    int tid = threadIdx.x;
    int lane = tid & 63, wave = tid >> 6;
    int wm = wave >> 2, wn = wave & 3;  // 2M x 4N, wave tile 64x32
    int cb = lane & 15, hi = lane >> 4;

    int bid = blockIdx.x;
    int by = bid >> 4, bx = bid & 15;  // XCD (bid&7) sees bx in {d, d+8}: B panels 1MB L2-res
    int bm = by * 128, bn = bx * 128;

    f32x4 acc[4][2];
#pragma unroll
    for (int m = 0; m < 4; m++)
#pragma unroll
        for (int n = 0; n < 2; n++) acc[m][n] = (f32x4){0.f, 0.f, 0.f, 0.f};

    int rp = tid >> 3, cc = tid & 7;
    int scol = ((cc ^ (rp & 7)) << 3);

    auto bufp = [&](int t) { return smem + (t % 3) * 16384; };
    auto stageA = [&](int t, int u) {
        gl_lds16(A + (size_t)(bm + u * 64 + rp) * K + (t << 6) + scol,
                 bufp(t) + u * 4096 + tid * 8);
    };
    auto stageB = [&](int t, int u) {
        gl_lds16(BT + (size_t)(bn + u * 64 + rp) * K + (t << 6) + scol,
                 bufp(t) + 8192 + u * 4096 + tid * 8);
    };

    f16x8 a[4][2], b0[2], b1[2];

    // prologue: tiles 0 and 1 (4 units each); confirm tile 0 (4 in flight)
    stageA(0, 0); stageA(0, 1); stageB(0, 0); stageB(0, 1);
    stageA(1, 0); stageA(1, 1); stageB(1, 0); stageB(1, 1);
    asm volatile("s_waitcnt vmcnt(4)" ::: "memory");
    __builtin_amdgcn_s_barrier();

    for (int t = 0; t < NT; t++) {
        const char* bA = (const char*)bufp(t);
        const char* bB = bA + 16384;
        // ---- ph0: read a(8) + b0(2); stage A0,A1(t+2); MFMA a x b0 ----
#pragma unroll
        for (int mf = 0; mf < 4; mf++) {
            int ra = wm * 64 + mf * 16 + cb;
#pragma unroll
            for (int ks = 0; ks < 2; ks++)
                a[mf][ks] = *(const f16x8*)(bA + (ra << 7) +
                                            ((ks * 64 + hi * 16) ^ ((ra & 7) << 4)));
        }
        {
            int rb = wn * 32 + cb;
#pragma unroll
            for (int ks = 0; ks < 2; ks++)
                b0[ks] = *(const f16x8*)(bB + (rb << 7) +
                                         ((ks * 64 + hi * 16) ^ ((rb & 7) << 4)));
        }
        if (t + 2 < NT) { stageA(t + 2, 0); stageA(t + 2, 1); }
        __builtin_amdgcn_s_barrier();
        asm volatile("s_waitcnt lgkmcnt(0)" ::: "memory");
        __builtin_amdgcn_s_setprio(1);
#pragma unroll
        for (int mf = 0; mf < 4; mf++)
#pragma unroll
            for (int ks = 0; ks < 2; ks++)
                acc[mf][0] = __builtin_amdgcn_mfma_f32_16x16x32_f16(a[mf][ks], b0[ks], acc[mf][0], 0, 0, 0);
        __builtin_amdgcn_s_setprio(0);
        __builtin_amdgcn_s_barrier();

        // ---- ph1: read b1(2); stage B0,B1(t+2); vmcnt; MFMA a x b1 ----
        {
            int rb = wn * 32 + 16 + cb;
#pragma unroll
            for (int ks = 0; ks < 2; ks++)
                b1[ks] = *(const f16x8*)(bB + (rb << 7) +
                                         ((ks * 64 + hi * 16) ^ ((rb & 7) << 4)));
        }
        if (t + 2 < NT) { stageB(t + 2, 0); stageB(t + 2, 1); }
        if (t < NT - 2)
            asm volatile("s_waitcnt vmcnt(4)" ::: "memory");
        else if (t == NT - 2)
            asm volatile("s_waitcnt vmcnt(0)" ::: "memory");
        __builtin_amdgcn_s_barrier();
        asm volatile("s_waitcnt lgkmcnt(0)" ::: "memory");
        __builtin_amdgcn_s_setprio(1);
#pragma unroll
        for (int mf = 0; mf < 4; mf++)
#pragma unroll
            for (int ks = 0; ks < 2; ks++)
                acc[mf][1] = __builtin_amdgcn_mfma_f32_16x16x32_f16(a[mf][ks], b1[ks], acc[mf][1], 0, 0, 0);
        __builtin_amdgcn_s_setprio(0);
        __builtin_amdgcn_s_barrier();
    }

    // epilogue: direct fp32 stores
#pragma unroll
    for (int mf = 0; mf < 4; mf++)
#pragma unroll
        for (int nf = 0; nf < 2; nf++) {
            int gn = bn + wn * 32 + nf * 16 + cb;
#pragma unroll
            for (int r = 0; r < 4; r++) {
                int gm = bm + wm * 64 + mf * 16 + hi * 4 + r;
                out[(size_t)gm * H_DIM + gn] = acc[mf][nf][r];
            }
        }
}

// ---------------- per-(block,head) attention (round-7 version, unchanged) ----------------
__global__ __launch_bounds__(256) void attn_kernel(const _Float16* __restrict__ qkvb,
                                                   const float* __restrict__ bias,
                                                   const float* __restrict__ mask,
                                                   _Float16* __restrict__ aout) {
    int bid = blockIdx.x;
    int n = bid >> 4, e = bid & 15;
    int t0 = n * KBLK;
    int valid = (T_DIM - t0 < KBLK) ? (T_DIM - t0) : KBLK;

    __shared__ _Float16 Qs[64 * 136];
    __shared__ _Float16 Ks[64 * 136];
    __shared__ _Float16 VTs[128 * 72];
    __shared__ _Float16 Ps[64 * 72];
    __shared__ float maskv[64];

    int tid = threadIdx.x;
    int lane = tid & 63, wave = tid >> 6;
    const _Float16* qp = qkvb + (size_t)e * (T_DIM * DH);
    const _Float16* kp = qkvb + (size_t)(T_DIM * H_DIM) + (size_t)e * (T_DIM * DH);
    const _Float16* vp = qkvb + (size_t)2 * (T_DIM * H_DIM) + (size_t)e * (T_DIM * DH);

#pragma unroll
    for (int i = 0; i < 4; i++) {
        int c = tid + i * 256;
        int r = c >> 4, c8 = c & 15;
        uint4 z = {0u, 0u, 0u, 0u};
        uint4 vq = z, vk = z;
        if (r < valid) {
            vq = *(const uint4*)&qp[(size_t)(t0 + r) * DH + c8 * 8];
            vk = *(const uint4*)&kp[(size_t)(t0 + r) * DH + c8 * 8];
        }
        *(uint4*)&Qs[r * 136 + c8 * 8] = vq;
        *(uint4*)&Ks[r * 136 + c8 * 8] = vk;
    }
#pragma unroll
    for (int i = 0; i < 4; i++) {
        int c = tid + i * 256;
        int r = c & 63;
        int f0 = (c >> 6) * 8;
        uint4 v = {0u, 0u, 0u, 0u};
        if (r < valid) v = *(const uint4*)&vp[(size_t)(t0 + r) * DH + f0];
        _Float16 tmp[8];
        *(uint4*)tmp = v;
#pragma unroll
        for (int j = 0; j < 8; j++) VTs[(f0 + j) * 72 + r] = tmp[j];
    }
    if (tid < 64) maskv[tid] = (tid < valid) ? mask[t0 + tid] : NEGV;
    __syncthreads();

    int qr0 = wave * 16;
    int cb = lane & 15, hi = lane >> 4;

    f16x8 aq[4];
#pragma unroll
    for (int ks = 0; ks < 4; ks++)
        aq[ks] = *(const f16x8*)&Qs[(qr0 + cb) * 136 + ks * 32 + hi * 8];
    f32x4 s[4];
#pragma unroll
    for (int kt = 0; kt < 4; kt++) s[kt] = (f32x4){0.f, 0.f, 0.f, 0.f};
#pragma unroll
    for (int kt = 0; kt < 4; kt++)
#pragma unroll
        for (int ks = 0; ks < 4; ks++) {
            f16x8 bk = *(const f16x8*)&Ks[(kt * 16 + cb) * 136 + ks * 32 + hi * 8];
            s[kt] = __builtin_amdgcn_mfma_f32_16x16x32_f16(aq[ks], bk, s[kt], 0, 0, 0);
        }

#pragma unroll
    for (int r = 0; r < 4; r++) {
        int rl = qr0 + hi * 4 + r;
        int qi = t0 + rl;
        float mq = maskv[rl];
        float lg[4];
        float mx = -3.4e38f;
#pragma unroll
        for (int kt = 0; kt < 4; kt++) {
            int cl = kt * 16 + cb, ki = t0 + cl;
            float bg = (qi < T_DIM && ki < T_DIM)
                           ? bias[((size_t)e * T_DIM + qi) * T_DIM + ki] : 0.f;
            float pr = mq * maskv[cl];
            float v = s[kt][r] + bg + (pr > 0.f ? 0.f : NEGV);
            lg[kt] = v;
            mx = fmaxf(mx, v);
        }
#pragma unroll
        for (int off = 8; off; off >>= 1) mx = fmaxf(mx, __shfl_xor(mx, off));
        float sum = 0.f;
#pragma unroll
        for (int kt = 0; kt < 4; kt++) {
            float pe = __expf(lg[kt] - mx);
            lg[kt] = pe;
            sum += pe;
        }
#pragma unroll
        for (int off = 8; off; off >>= 1) sum += __shfl_xor(sum, off);
        float inv = 1.f / sum;
#pragma unroll
        for (int kt = 0; kt < 4; kt++)
            Ps[rl * 72 + kt * 16 + cb] = (_Float16)(lg[kt] * inv);
    }
    __syncthreads();

    f16x8 pa[2];
#pragma unroll
    for (int ks = 0; ks < 2; ks++)
        pa[ks] = *(const f16x8*)&Ps[(qr0 + cb) * 72 + ks * 32 + hi * 8];
#pragma unroll
    for (int ft = 0; ft < 8; ft++) {
        f32x4 o = (f32x4){0.f, 0.f, 0.f, 0.f};
#pragma unroll
        for (int ks = 0; ks < 2; ks++) {
            f16x8 bv = *(const f16x8*)&VTs[(ft * 16 + cb) * 72 + ks * 32 + hi * 8];
            o = __builtin_amdgcn_mfma_f32_16x16x32_f16(pa[ks], bv, o, 0, 0, 0);
        }
#pragma unroll
        for (int r = 0; r < 4; r++) {
            int rl = qr0 + hi * 4 + r;
            if (rl < valid)
                aout[(size_t)(t0 + rl) * H_DIM + e * DH + ft * 16 + cb] = (_Float16)o[r];
        }
    }
}

extern "C" void kernel_launch(void* const* d_in, const int* in_sizes, int n_in,
                              void* d_out, int out_size, void* d_ws, size_t ws_size,
                              hipStream_t stream) {
    const float* x    = (const float*)d_in[0];
    const float* mask = (const float*)d_in[1];
    const float* bias = (const float*)d_in[2];
    const float* Wq   = (const float*)d_in[3];
    const float* Wk   = (const float*)d_in[4];
    const float* Wv   = (const float*)d_in[5];
    const float* Wo   = (const float*)d_in[6];
    float* out = (float*)d_out;

    // ws layout (f16): xb[4M] | WT[12M] | WoT[4M] | qkv[12M] | aout[4M] = 72MB
    _Float16* xb   = (_Float16*)d_ws;
    _Float16* WT   = xb + (size_t)T_DIM * H_DIM;
    _Float16* WoT  = WT + (size_t)3 * T_DIM * H_DIM;
    _Float16* qkvb = WoT + (size_t)T_DIM * H_DIM;
    _Float16* aout = qkvb + (size_t)3 * T_DIM * H_DIM;

    prep_kernel<<<dim3(64, 64, 5), dim3(32, 8), 0, stream>>>(x, Wq, Wk, Wv, Wo, xb, WT, WoT);

    qkv192_kernel<<<256, 512, 0, stream>>>(xb, WT, qkvb);

    attn_kernel<<<NBLK * N_HEADS, 256, 0, stream>>>(qkvb, bias, mask, aout);

    // out-proj: 128x128 tiles, full-K fp32 accumulation, direct fp32 output
    oproj_kernel<<<256, 512, 0, stream>>>(aout, WoT, out);
}

// Round 10
// 116.272 us; speedup vs baseline: 1.1307x; 1.0269x over previous
//
#include <hip/hip_runtime.h>
#include <hip/hip_bf16.h>

typedef _Float16 f16x8 __attribute__((ext_vector_type(8)));
typedef float f32x4 __attribute__((ext_vector_type(4)));

#define T_DIM 2048
#define H_DIM 2048
#define N_HEADS 16
#define DH 128
#define KBLK 50
#define NBLK 41
#define NEGV (-1.0e9f)
#define QSCALE 0.08838834764831845f  // 128^-0.5

__device__ __forceinline__ void gl_lds16(const void* g, void* l) {
    __builtin_amdgcn_global_load_lds(
        (const __attribute__((address_space(1))) void*)g,
        (__attribute__((address_space(3))) void*)l, 16, 0, 0);
}

// ---- fused prep: z<4 weight transpose fp32->fp16; z==4 x convert (round-7, proven) ----
__global__ __launch_bounds__(256) void prep_kernel(const float* __restrict__ x,
                                                   const float* __restrict__ Wq,
                                                   const float* __restrict__ Wk,
                                                   const float* __restrict__ Wv,
                                                   const float* __restrict__ Wo,
                                                   _Float16* __restrict__ xb,
                                                   _Float16* __restrict__ WT,
                                                   _Float16* __restrict__ WoT) {
    __shared__ float tile[32][33];
    int z = blockIdx.z;
    int tx = threadIdx.x, ty = threadIdx.y;  // 32 x 8
    if (z == 4) {
        if (blockIdx.y >= 32) return;
        int flat = blockIdx.y * 64 + blockIdx.x;
        int i = (flat * 256 + ty * 32 + tx) * 8;
        float4 a = *(const float4*)&x[i];
        float4 b = *(const float4*)&x[i + 4];
        f16x8 o = {(_Float16)a.x, (_Float16)a.y, (_Float16)a.z, (_Float16)a.w,
                   (_Float16)b.x, (_Float16)b.y, (_Float16)b.z, (_Float16)b.w};
        *(f16x8*)&xb[i] = o;
        return;
    }
    const float* src = (z == 0) ? Wq : (z == 1) ? Wk : (z == 2) ? Wv : Wo;
    _Float16* dst = (z == 3) ? WoT : (WT + (size_t)z * T_DIM * H_DIM);
    int bx = blockIdx.x * 32, by = blockIdx.y * 32;
#pragma unroll
    for (int i = 0; i < 4; i++)
        tile[ty + i * 8][tx] = src[(size_t)(by + ty + i * 8) * H_DIM + bx + tx];
    __syncthreads();
#pragma unroll
    for (int i = 0; i < 4; i++)
        dst[(size_t)(bx + ty + i * 8) * H_DIM + by + tx] = (_Float16)tile[tx][ty + i * 8];
}

// =============== QKV projection: 128x192 tile, 4-phase, 512 blocks = 2/CU ===============
// Same proven 7-unit ledger as round-7 qkv192, halved to 256 threads / 80KB LDS so two
// independent blocks co-reside per CU (barrier drains decorrelate).
// Units (1 gl_lds/thread = 4KB): A0..A3 (32 rows each), B0..B5. Issue order per wave:
// A(t+1)@(t-1,ph2/ph3), B(t+1)@(t,ph0/ph1), A(t+2)@(t,ph2/ph3) -> vmcnt(4) at ph3
// confirms tile t+1 (newest 4 = A(t+2)). Tail vmcnt(0) at NT-2.
__global__ __launch_bounds__(256, 2) void qkv_kernel(const _Float16* __restrict__ A,
                                                     const _Float16* __restrict__ BT,
                                                     _Float16* __restrict__ qkv) {
    const int K = 2048, NT = 32;
    __shared__ _Float16 smem[40960];  // 80KB: A dbuf 2x8192 | B dbuf 2x12288
    _Float16* sA0 = smem;
    _Float16* sA1 = smem + 8192;
    _Float16* sB0 = smem + 16384;
    _Float16* sB1 = smem + 28672;

    int tid = threadIdx.x;
    int lane = tid & 63, wave = tid >> 6;
    int wm = wave >> 1, wn = wave & 1;  // 2M x 2N, wave tile 64x96
    int cb = lane & 15, hi = lane >> 4;

    int bid = blockIdx.x;
    int by = bid >> 5, bx = bid & 31;
    int bm = by * 128, bn = bx * 192;

    f32x4 acc[4][6];
#pragma unroll
    for (int m = 0; m < 4; m++)
#pragma unroll
        for (int n = 0; n < 6; n++) acc[m][n] = (f32x4){0.f, 0.f, 0.f, 0.f};

    int rp = tid >> 3, cc = tid & 7;  // 32 rows/unit, 8 chunks/row
    int scol = ((cc ^ (rp & 7)) << 3);

    auto stageA = [&](int t, int u) {
        gl_lds16(A + (size_t)(bm + u * 32 + rp) * K + (t << 6) + scol,
                 ((t & 1) ? sA1 : sA0) + u * 2048 + tid * 8);
    };
    auto stageB = [&](int t, int u) {
        gl_lds16(BT + (size_t)(bn + u * 32 + rp) * K + (t << 6) + scol,
                 ((t & 1) ? sB1 : sB0) + u * 2048 + tid * 8);
    };

    f16x8 a[4][2], b[6][2];

    // prologue: tile0 (A0-3,B0-5) + A(1); vmcnt(4) -> tile0 landed
    stageA(0, 0); stageA(0, 1); stageA(0, 2); stageA(0, 3);
    stageB(0, 0); stageB(0, 1); stageB(0, 2); stageB(0, 3); stageB(0, 4); stageB(0, 5);
    stageA(1, 0); stageA(1, 1); stageA(1, 2); stageA(1, 3);
    asm volatile("s_waitcnt vmcnt(4)" ::: "memory");
    __builtin_amdgcn_s_barrier();

    for (int t = 0; t < NT; t++) {
        int buf = t & 1;
        const char* bA = (const char*)(buf ? sA1 : sA0);
        const char* bB = (const char*)(buf ? sB1 : sB0);
        // ---- ph0: read a(8) + b012(6); stage B012(t+1); MFMA m01 x n012 ----
#pragma unroll
        for (int mf = 0; mf < 4; mf++) {
            int ra = wm * 64 + mf * 16 + cb;
#pragma unroll
            for (int ks = 0; ks < 2; ks++)
                a[mf][ks] = *(const f16x8*)(bA + (ra << 7) +
                                            ((ks * 64 + hi * 16) ^ ((ra & 7) << 4)));
        }
#pragma unroll
        for (int nf = 0; nf < 3; nf++) {
            int rb = wn * 96 + nf * 16 + cb;
#pragma unroll
            for (int ks = 0; ks < 2; ks++)
                b[nf][ks] = *(const f16x8*)(bB + (rb << 7) +
                                            ((ks * 64 + hi * 16) ^ ((rb & 7) << 4)));
        }
        if (t + 1 < NT) { stageB(t + 1, 0); stageB(t + 1, 1); stageB(t + 1, 2); }
        __builtin_amdgcn_s_barrier();
        asm volatile("s_waitcnt lgkmcnt(0)" ::: "memory");
        __builtin_amdgcn_s_setprio(1);
#pragma unroll
        for (int mf = 0; mf < 2; mf++)
#pragma unroll
            for (int nf = 0; nf < 3; nf++)
#pragma unroll
                for (int ks = 0; ks < 2; ks++)
                    acc[mf][nf] = __builtin_amdgcn_mfma_f32_16x16x32_f16(a[mf][ks], b[nf][ks], acc[mf][nf], 0, 0, 0);
        __builtin_amdgcn_s_setprio(0);
        __builtin_amdgcn_s_barrier();

        // ---- ph1: read b345(6); stage B345(t+1); MFMA m01 x n345 ----
#pragma unroll
        for (int nf = 3; nf < 6; nf++) {
            int rb = wn * 96 + nf * 16 + cb;
#pragma unroll
            for (int ks = 0; ks < 2; ks++)
                b[nf][ks] = *(const f16x8*)(bB + (rb << 7) +
                                            ((ks * 64 + hi * 16) ^ ((rb & 7) << 4)));
        }
        if (t + 1 < NT) { stageB(t + 1, 3); stageB(t + 1, 4); stageB(t + 1, 5); }
        __builtin_amdgcn_s_barrier();
        asm volatile("s_waitcnt lgkmcnt(0)" ::: "memory");
        __builtin_amdgcn_s_setprio(1);
#pragma unroll
        for (int mf = 0; mf < 2; mf++)
#pragma unroll
            for (int nf = 3; nf < 6; nf++)
#pragma unroll
                for (int ks = 0; ks < 2; ks++)
                    acc[mf][nf] = __builtin_amdgcn_mfma_f32_16x16x32_f16(a[mf][ks], b[nf][ks], acc[mf][nf], 0, 0, 0);
        __builtin_amdgcn_s_setprio(0);
        __builtin_amdgcn_s_barrier();

        // ---- ph2: stage A01(t+2); MFMA m23 x n012 ----
        if (t + 2 < NT) { stageA(t + 2, 0); stageA(t + 2, 1); }
        __builtin_amdgcn_s_barrier();
        __builtin_amdgcn_s_setprio(1);
#pragma unroll
        for (int mf = 2; mf < 4; mf++)
#pragma unroll
            for (int nf = 0; nf < 3; nf++)
#pragma unroll
                for (int ks = 0; ks < 2; ks++)
                    acc[mf][nf] = __builtin_amdgcn_mfma_f32_16x16x32_f16(a[mf][ks], b[nf][ks], acc[mf][nf], 0, 0, 0);
        __builtin_amdgcn_s_setprio(0);
        __builtin_amdgcn_s_barrier();

        // ---- ph3: stage A23(t+2); vmcnt confirms tile t+1; MFMA m23 x n345 ----
        if (t + 2 < NT) { stageA(t + 2, 2); stageA(t + 2, 3); }
        if (t < NT - 2)
            asm volatile("s_waitcnt vmcnt(4)" ::: "memory");
        else if (t == NT - 2)
            asm volatile("s_waitcnt vmcnt(0)" ::: "memory");
        __builtin_amdgcn_s_barrier();
        __builtin_amdgcn_s_setprio(1);
#pragma unroll
        for (int mf = 2; mf < 4; mf++)
#pragma unroll
            for (int nf = 3; nf < 6; nf++)
#pragma unroll
                for (int ks = 0; ks < 2; ks++)
                    acc[mf][nf] = __builtin_amdgcn_mfma_f32_16x16x32_f16(a[mf][ks], b[nf][ks], acc[mf][nf], 0, 0, 0);
        __builtin_amdgcn_s_setprio(0);
        __builtin_amdgcn_s_barrier();
    }

    // epilogue: single-pass LDS repack [128][200] (50KB) -> coalesced uint4 scatter
#pragma unroll
    for (int mf = 0; mf < 4; mf++)
#pragma unroll
        for (int nf = 0; nf < 6; nf++) {
            int col = wn * 96 + nf * 16 + cb;
            float sc = ((bn + col) >> 11) == 0 ? QSCALE : 1.0f;
#pragma unroll
            for (int r = 0; r < 4; r++) {
                int row = wm * 64 + mf * 16 + hi * 4 + r;
                smem[row * 200 + col] = (_Float16)(acc[mf][nf][r] * sc);
            }
        }
    __builtin_amdgcn_s_barrier();
#pragma unroll
    for (int it = 0; it < 12; it++) {
        int c = it * 256 + tid;  // 3072 chunks = 128 rows x 24
        int row = c / 24, col8 = c - row * 24;
        int gm = bm + row;
        int gn = bn + col8 * 8;
        int tensor = gn >> 11;
        int ef = gn & 2047;
        int e = ef >> 7, f0 = ef & 127;
        uint4 v = *(const uint4*)&smem[row * 200 + col8 * 8];
        *(uint4*)(qkv + (size_t)tensor * (T_DIM * H_DIM) + (size_t)e * (T_DIM * DH) +
                  (size_t)gm * DH + f0) = v;
    }
}

// =============== out-proj: 128x64 tile, full K, fp32 out, 512 blocks = 2/CU ==============
// Round-9 triple-buffer counted-vmcnt ledger at 256 threads / 72KB LDS.
// 6 instr/tile (A=4 units, B=2). vmcnt(6) at (t,ph1) confirms tile t+1 (newest 6 = t+2).
__global__ __launch_bounds__(256, 2) void oproj_kernel(const _Float16* __restrict__ A,
                                                       const _Float16* __restrict__ BT,
                                                       float* __restrict__ out) {
    const int K = 2048, NT = 32;
    __shared__ _Float16 smem[36864];  // 72KB: 3 bufs x (A 8192 | B 4096) f16

    int tid = threadIdx.x;
    int lane = tid & 63, wave = tid >> 6;
    int wm = wave >> 1, wn = wave & 1;  // 2M x 2N, wave tile 64x32
    int cb = lane & 15, hi = lane >> 4;

    int bid = blockIdx.x;
    int by = bid >> 5, bx = bid & 31;
    int bm = by * 128, bn = bx * 64;

    f32x4 acc[4][2];
#pragma unroll
    for (int m = 0; m < 4; m++)
#pragma unroll
        for (int n = 0; n < 2; n++) acc[m][n] = (f32x4){0.f, 0.f, 0.f, 0.f};

    int rp = tid >> 3, cc = tid & 7;
    int scol = ((cc ^ (rp & 7)) << 3);

    auto bufp = [&](int t) { return smem + (t % 3) * 12288; };
    auto stageA = [&](int t, int u) {
        gl_lds16(A + (size_t)(bm + u * 32 + rp) * K + (t << 6) + scol,
                 bufp(t) + u * 2048 + tid * 8);
    };
    auto stageB = [&](int t, int u) {
        gl_lds16(BT + (size_t)(bn + u * 32 + rp) * K + (t << 6) + scol,
                 bufp(t) + 8192 + u * 2048 + tid * 8);
    };

    f16x8 a[4][2], b0[2], b1[2];

    stageA(0, 0); stageA(0, 1); stageA(0, 2); stageA(0, 3); stageB(0, 0); stageB(0, 1);
    stageA(1, 0); stageA(1, 1); stageA(1, 2); stageA(1, 3); stageB(1, 0); stageB(1, 1);
    asm volatile("s_waitcnt vmcnt(6)" ::: "memory");
    __builtin_amdgcn_s_barrier();

    for (int t = 0; t < NT; t++) {
        const char* bA = (const char*)bufp(t);
        const char* bB = bA + 16384;  // 8192 f16 = 16384 B
        // ---- ph0: read a(8) + b0(2); stage A(t+2) x4; MFMA a x b0 ----
#pragma unroll
        for (int mf = 0; mf < 4; mf++) {
            int ra = wm * 64 + mf * 16 + cb;
#pragma unroll
            for (int ks = 0; ks < 2; ks++)
                a[mf][ks] = *(const f16x8*)(bA + (ra << 7) +
                                            ((ks * 64 + hi * 16) ^ ((ra & 7) << 4)));
        }
        {
            int rb = wn * 32 + cb;
#pragma unroll
            for (int ks = 0; ks < 2; ks++)
                b0[ks] = *(const f16x8*)(bB + (rb << 7) +
                                         ((ks * 64 + hi * 16) ^ ((rb & 7) << 4)));
        }
        if (t + 2 < NT) { stageA(t + 2, 0); stageA(t + 2, 1); stageA(t + 2, 2); stageA(t + 2, 3); }
        __builtin_amdgcn_s_barrier();
        asm volatile("s_waitcnt lgkmcnt(0)" ::: "memory");
        __builtin_amdgcn_s_setprio(1);
#pragma unroll
        for (int mf = 0; mf < 4; mf++)
#pragma unroll
            for (int ks = 0; ks < 2; ks++)
                acc[mf][0] = __builtin_amdgcn_mfma_f32_16x16x32_f16(a[mf][ks], b0[ks], acc[mf][0], 0, 0, 0);
        __builtin_amdgcn_s_setprio(0);
        __builtin_amdgcn_s_barrier();

        // ---- ph1: read b1(2); stage B(t+2) x2; vmcnt; MFMA a x b1 ----
        {
            int rb = wn * 32 + 16 + cb;
#pragma unroll
            for (int ks = 0; ks < 2; ks++)
                b1[ks] = *(const f16x8*)(bB + (rb << 7) +
                                         ((ks * 64 + hi * 16) ^ ((rb & 7) << 4)));
        }
        if (t + 2 < NT) { stageB(t + 2, 0); stageB(t + 2, 1); }
        if (t < NT - 2)
            asm volatile("s_waitcnt vmcnt(6)" ::: "memory");
        else if (t == NT - 2)
            asm volatile("s_waitcnt vmcnt(0)" ::: "memory");
        __builtin_amdgcn_s_barrier();
        asm volatile("s_waitcnt lgkmcnt(0)" ::: "memory");
        __builtin_amdgcn_s_setprio(1);
#pragma unroll
        for (int mf = 0; mf < 4; mf++)
#pragma unroll
            for (int ks = 0; ks < 2; ks++)
                acc[mf][1] = __builtin_amdgcn_mfma_f32_16x16x32_f16(a[mf][ks], b1[ks], acc[mf][1], 0, 0, 0);
        __builtin_amdgcn_s_setprio(0);
        __builtin_amdgcn_s_barrier();
    }

    // epilogue: direct fp32 stores
#pragma unroll
    for (int mf = 0; mf < 4; mf++)
#pragma unroll
        for (int nf = 0; nf < 2; nf++) {
            int gn = bn + wn * 32 + nf * 16 + cb;
#pragma unroll
            for (int r = 0; r < 4; r++) {
                int gm = bm + wm * 64 + mf * 16 + hi * 4 + r;
                out[(size_t)gm * H_DIM + gn] = acc[mf][nf][r];
            }
        }
}

// ---------------- per-(block,head) attention (round-9 version, unchanged) ----------------
__global__ __launch_bounds__(256) void attn_kernel(const _Float16* __restrict__ qkvb,
                                                   const float* __restrict__ bias,
                                                   const float* __restrict__ mask,
                                                   _Float16* __restrict__ aout) {
    int bid = blockIdx.x;
    int n = bid >> 4, e = bid & 15;
    int t0 = n * KBLK;
    int valid = (T_DIM - t0 < KBLK) ? (T_DIM - t0) : KBLK;

    __shared__ _Float16 Qs[64 * 136];
    __shared__ _Float16 Ks[64 * 136];
    __shared__ _Float16 VTs[128 * 72];
    __shared__ _Float16 Ps[64 * 72];
    __shared__ float maskv[64];

    int tid = threadIdx.x;
    int lane = tid & 63, wave = tid >> 6;
    const _Float16* qp = qkvb + (size_t)e * (T_DIM * DH);
    const _Float16* kp = qkvb + (size_t)(T_DIM * H_DIM) + (size_t)e * (T_DIM * DH);
    const _Float16* vp = qkvb + (size_t)2 * (T_DIM * H_DIM) + (size_t)e * (T_DIM * DH);

#pragma unroll
    for (int i = 0; i < 4; i++) {
        int c = tid + i * 256;
        int r = c >> 4, c8 = c & 15;
        uint4 z = {0u, 0u, 0u, 0u};
        uint4 vq = z, vk = z;
        if (r < valid) {
            vq = *(const uint4*)&qp[(size_t)(t0 + r) * DH + c8 * 8];
            vk = *(const uint4*)&kp[(size_t)(t0 + r) * DH + c8 * 8];
        }
        *(uint4*)&Qs[r * 136 + c8 * 8] = vq;
        *(uint4*)&Ks[r * 136 + c8 * 8] = vk;
    }
#pragma unroll
    for (int i = 0; i < 4; i++) {
        int c = tid + i * 256;
        int r = c & 63;
        int f0 = (c >> 6) * 8;
        uint4 v = {0u, 0u, 0u, 0u};
        if (r < valid) v = *(const uint4*)&vp[(size_t)(t0 + r) * DH + f0];
        _Float16 tmp[8];
        *(uint4*)tmp = v;
#pragma unroll
        for (int j = 0; j < 8; j++) VTs[(f0 + j) * 72 + r] = tmp[j];
    }
    if (tid < 64) maskv[tid] = (tid < valid) ? mask[t0 + tid] : NEGV;
    __syncthreads();

    int qr0 = wave * 16;
    int cb = lane & 15, hi = lane >> 4;

    f16x8 aq[4];
#pragma unroll
    for (int ks = 0; ks < 4; ks++)
        aq[ks] = *(const f16x8*)&Qs[(qr0 + cb) * 136 + ks * 32 + hi * 8];
    f32x4 s[4];
#pragma unroll
    for (int kt = 0; kt < 4; kt++) s[kt] = (f32x4){0.f, 0.f, 0.f, 0.f};
#pragma unroll
    for (int kt = 0; kt < 4; kt++)
#pragma unroll
        for (int ks = 0; ks < 4; ks++) {
            f16x8 bk = *(const f16x8*)&Ks[(kt * 16 + cb) * 136 + ks * 32 + hi * 8];
            s[kt] = __builtin_amdgcn_mfma_f32_16x16x32_f16(aq[ks], bk, s[kt], 0, 0, 0);
        }

#pragma unroll
    for (int r = 0; r < 4; r++) {
        int rl = qr0 + hi * 4 + r;
        int qi = t0 + rl;
        float mq = maskv[rl];
        float lg[4];
        float mx = -3.4e38f;
#pragma unroll
        for (int kt = 0; kt < 4; kt++) {
            int cl = kt * 16 + cb, ki = t0 + cl;
            float bg = (qi < T_DIM && ki < T_DIM)
                           ? bias[((size_t)e * T_DIM + qi) * T_DIM + ki] : 0.f;
            float pr = mq * maskv[cl];
            float v = s[kt][r] + bg + (pr > 0.f ? 0.f : NEGV);
            lg[kt] = v;
            mx = fmaxf(mx, v);
        }
#pragma unroll
        for (int off = 8; off; off >>= 1) mx = fmaxf(mx, __shfl_xor(mx, off));
        float sum = 0.f;
#pragma unroll
        for (int kt = 0; kt < 4; kt++) {
            float pe = __expf(lg[kt] - mx);
            lg[kt] = pe;
            sum += pe;
        }
#pragma unroll
        for (int off = 8; off; off >>= 1) sum += __shfl_xor(sum, off);
        float inv = 1.f / sum;
#pragma unroll
        for (int kt = 0; kt < 4; kt++)
            Ps[rl * 72 + kt * 16 + cb] = (_Float16)(lg[kt] * inv);
    }
    __syncthreads();

    f16x8 pa[2];
#pragma unroll
    for (int ks = 0; ks < 2; ks++)
        pa[ks] = *(const f16x8*)&Ps[(qr0 + cb) * 72 + ks * 32 + hi * 8];
#pragma unroll
    for (int ft = 0; ft < 8; ft++) {
        f32x4 o = (f32x4){0.f, 0.f, 0.f, 0.f};
#pragma unroll
        for (int ks = 0; ks < 2; ks++) {
            f16x8 bv = *(const f16x8*)&VTs[(ft * 16 + cb) * 72 + ks * 32 + hi * 8];
            o = __builtin_amdgcn_mfma_f32_16x16x32_f16(pa[ks], bv, o, 0, 0, 0);
        }
#pragma unroll
        for (int r = 0; r < 4; r++) {
            int rl = qr0 + hi * 4 + r;
            if (rl < valid)
                aout[(size_t)(t0 + rl) * H_DIM + e * DH + ft * 16 + cb] = (_Float16)o[r];
        }
    }
}

extern "C" void kernel_launch(void* const* d_in, const int* in_sizes, int n_in,
                              void* d_out, int out_size, void* d_ws, size_t ws_size,
                              hipStream_t stream) {
    const float* x    = (const float*)d_in[0];
    const float* mask = (const float*)d_in[1];
    const float* bias = (const float*)d_in[2];
    const float* Wq   = (const float*)d_in[3];
    const float* Wk   = (const float*)d_in[4];
    const float* Wv   = (const float*)d_in[5];
    const float* Wo   = (const float*)d_in[6];
    float* out = (float*)d_out;

    // ws layout (f16): xb[4M] | WT[12M] | WoT[4M] | qkv[12M] | aout[4M] = 72MB
    _Float16* xb   = (_Float16*)d_ws;
    _Float16* WT   = xb + (size_t)T_DIM * H_DIM;
    _Float16* WoT  = WT + (size_t)3 * T_DIM * H_DIM;
    _Float16* qkvb = WoT + (size_t)T_DIM * H_DIM;
    _Float16* aout = qkvb + (size_t)3 * T_DIM * H_DIM;

    prep_kernel<<<dim3(64, 64, 5), dim3(32, 8), 0, stream>>>(x, Wq, Wk, Wv, Wo, xb, WT, WoT);

    // QKV projection: 128x192 tiles -> 512 blocks (2/CU)
    qkv_kernel<<<512, 256, 0, stream>>>(xb, WT, qkvb);

    attn_kernel<<<NBLK * N_HEADS, 256, 0, stream>>>(qkvb, bias, mask, aout);

    // out-proj: 128x64 tiles -> 512 blocks (2/CU), full-K fp32, direct output
    oproj_kernel<<<512, 256, 0, stream>>>(aout, WoT, out);
}

// Round 11
// 113.634 us; speedup vs baseline: 1.1569x; 1.0232x over previous
//
#include <hip/hip_runtime.h>
#include <hip/hip_bf16.h>

typedef _Float16 f16x8 __attribute__((ext_vector_type(8)));
typedef float f32x4 __attribute__((ext_vector_type(4)));

#define T_DIM 2048
#define H_DIM 2048
#define N_HEADS 16
#define DH 128
#define KBLK 50
#define NBLK 41
#define NEGV (-1.0e9f)
#define QSCALE 0.08838834764831845f  // 128^-0.5

__device__ __forceinline__ void gl_lds16(const void* g, void* l) {
    __builtin_amdgcn_global_load_lds(
        (const __attribute__((address_space(1))) void*)g,
        (__attribute__((address_space(3))) void*)l, 16, 0, 0);
}

// ---- prep: z<3 -> transpose Wq/Wk/Wv fp32->fp16; z==3 -> convert x fp32->fp16 ----
// (Wo transpose moved into attn_kernel's extra blocks -- off the critical path.)
__global__ __launch_bounds__(256) void prep_kernel(const float* __restrict__ x,
                                                   const float* __restrict__ Wq,
                                                   const float* __restrict__ Wk,
                                                   const float* __restrict__ Wv,
                                                   _Float16* __restrict__ xb,
                                                   _Float16* __restrict__ WT) {
    __shared__ float tile[32][33];
    int z = blockIdx.z;
    int tx = threadIdx.x, ty = threadIdx.y;  // 32 x 8
    if (z == 3) {
        if (blockIdx.y >= 32) return;
        int flat = blockIdx.y * 64 + blockIdx.x;
        int i = (flat * 256 + ty * 32 + tx) * 8;
        float4 a = *(const float4*)&x[i];
        float4 b = *(const float4*)&x[i + 4];
        f16x8 o = {(_Float16)a.x, (_Float16)a.y, (_Float16)a.z, (_Float16)a.w,
                   (_Float16)b.x, (_Float16)b.y, (_Float16)b.z, (_Float16)b.w};
        *(f16x8*)&xb[i] = o;
        return;
    }
    const float* src = (z == 0) ? Wq : (z == 1) ? Wk : Wv;
    _Float16* dst = WT + (size_t)z * T_DIM * H_DIM;
    int bx = blockIdx.x * 32, by = blockIdx.y * 32;
#pragma unroll
    for (int i = 0; i < 4; i++)
        tile[ty + i * 8][tx] = src[(size_t)(by + ty + i * 8) * H_DIM + bx + tx];
    __syncthreads();
#pragma unroll
    for (int i = 0; i < 4; i++)
        dst[(size_t)(bx + ty + i * 8) * H_DIM + by + tx] = (_Float16)tile[tx][ty + i * 8];
}

// =============== QKV projection: 128x192 tile, 4-phase, 512 blocks = 2/CU (r10) ==========
__global__ __launch_bounds__(256, 2) void qkv_kernel(const _Float16* __restrict__ A,
                                                     const _Float16* __restrict__ BT,
                                                     _Float16* __restrict__ qkv) {
    const int K = 2048, NT = 32;
    __shared__ _Float16 smem[40960];  // 80KB: A dbuf 2x8192 | B dbuf 2x12288
    _Float16* sA0 = smem;
    _Float16* sA1 = smem + 8192;
    _Float16* sB0 = smem + 16384;
    _Float16* sB1 = smem + 28672;

    int tid = threadIdx.x;
    int lane = tid & 63, wave = tid >> 6;
    int wm = wave >> 1, wn = wave & 1;  // 2M x 2N, wave tile 64x96
    int cb = lane & 15, hi = lane >> 4;

    int bid = blockIdx.x;
    int by = bid >> 5, bx = bid & 31;
    int bm = by * 128, bn = bx * 192;

    f32x4 acc[4][6];
#pragma unroll
    for (int m = 0; m < 4; m++)
#pragma unroll
        for (int n = 0; n < 6; n++) acc[m][n] = (f32x4){0.f, 0.f, 0.f, 0.f};

    int rp = tid >> 3, cc = tid & 7;  // 32 rows/unit, 8 chunks/row
    int scol = ((cc ^ (rp & 7)) << 3);

    auto stageA = [&](int t, int u) {
        gl_lds16(A + (size_t)(bm + u * 32 + rp) * K + (t << 6) + scol,
                 ((t & 1) ? sA1 : sA0) + u * 2048 + tid * 8);
    };
    auto stageB = [&](int t, int u) {
        gl_lds16(BT + (size_t)(bn + u * 32 + rp) * K + (t << 6) + scol,
                 ((t & 1) ? sB1 : sB0) + u * 2048 + tid * 8);
    };

    f16x8 a[4][2], b[6][2];

    stageA(0, 0); stageA(0, 1); stageA(0, 2); stageA(0, 3);
    stageB(0, 0); stageB(0, 1); stageB(0, 2); stageB(0, 3); stageB(0, 4); stageB(0, 5);
    stageA(1, 0); stageA(1, 1); stageA(1, 2); stageA(1, 3);
    asm volatile("s_waitcnt vmcnt(4)" ::: "memory");
    __builtin_amdgcn_s_barrier();

    for (int t = 0; t < NT; t++) {
        int buf = t & 1;
        const char* bA = (const char*)(buf ? sA1 : sA0);
        const char* bB = (const char*)(buf ? sB1 : sB0);
        // ---- ph0: read a(8) + b012(6); stage B012(t+1); MFMA m01 x n012 ----
#pragma unroll
        for (int mf = 0; mf < 4; mf++) {
            int ra = wm * 64 + mf * 16 + cb;
#pragma unroll
            for (int ks = 0; ks < 2; ks++)
                a[mf][ks] = *(const f16x8*)(bA + (ra << 7) +
                                            ((ks * 64 + hi * 16) ^ ((ra & 7) << 4)));
        }
#pragma unroll
        for (int nf = 0; nf < 3; nf++) {
            int rb = wn * 96 + nf * 16 + cb;
#pragma unroll
            for (int ks = 0; ks < 2; ks++)
                b[nf][ks] = *(const f16x8*)(bB + (rb << 7) +
                                            ((ks * 64 + hi * 16) ^ ((rb & 7) << 4)));
        }
        if (t + 1 < NT) { stageB(t + 1, 0); stageB(t + 1, 1); stageB(t + 1, 2); }
        __builtin_amdgcn_s_barrier();
        asm volatile("s_waitcnt lgkmcnt(0)" ::: "memory");
        __builtin_amdgcn_s_setprio(1);
#pragma unroll
        for (int mf = 0; mf < 2; mf++)
#pragma unroll
            for (int nf = 0; nf < 3; nf++)
#pragma unroll
                for (int ks = 0; ks < 2; ks++)
                    acc[mf][nf] = __builtin_amdgcn_mfma_f32_16x16x32_f16(a[mf][ks], b[nf][ks], acc[mf][nf], 0, 0, 0);
        __builtin_amdgcn_s_setprio(0);
        __builtin_amdgcn_s_barrier();

        // ---- ph1: read b345(6); stage B345(t+1); MFMA m01 x n345 ----
#pragma unroll
        for (int nf = 3; nf < 6; nf++) {
            int rb = wn * 96 + nf * 16 + cb;
#pragma unroll
            for (int ks = 0; ks < 2; ks++)
                b[nf][ks] = *(const f16x8*)(bB + (rb << 7) +
                                            ((ks * 64 + hi * 16) ^ ((rb & 7) << 4)));
        }
        if (t + 1 < NT) { stageB(t + 1, 3); stageB(t + 1, 4); stageB(t + 1, 5); }
        __builtin_amdgcn_s_barrier();
        asm volatile("s_waitcnt lgkmcnt(0)" ::: "memory");
        __builtin_amdgcn_s_setprio(1);
#pragma unroll
        for (int mf = 0; mf < 2; mf++)
#pragma unroll
            for (int nf = 3; nf < 6; nf++)
#pragma unroll
                for (int ks = 0; ks < 2; ks++)
                    acc[mf][nf] = __builtin_amdgcn_mfma_f32_16x16x32_f16(a[mf][ks], b[nf][ks], acc[mf][nf], 0, 0, 0);
        __builtin_amdgcn_s_setprio(0);
        __builtin_amdgcn_s_barrier();

        // ---- ph2: stage A01(t+2); MFMA m23 x n012 ----
        if (t + 2 < NT) { stageA(t + 2, 0); stageA(t + 2, 1); }
        __builtin_amdgcn_s_barrier();
        __builtin_amdgcn_s_setprio(1);
#pragma unroll
        for (int mf = 2; mf < 4; mf++)
#pragma unroll
            for (int nf = 0; nf < 3; nf++)
#pragma unroll
                for (int ks = 0; ks < 2; ks++)
                    acc[mf][nf] = __builtin_amdgcn_mfma_f32_16x16x32_f16(a[mf][ks], b[nf][ks], acc[mf][nf], 0, 0, 0);
        __builtin_amdgcn_s_setprio(0);
        __builtin_amdgcn_s_barrier();

        // ---- ph3: stage A23(t+2); vmcnt confirms tile t+1; MFMA m23 x n345 ----
        if (t + 2 < NT) { stageA(t + 2, 2); stageA(t + 2, 3); }
        if (t < NT - 2)
            asm volatile("s_waitcnt vmcnt(4)" ::: "memory");
        else if (t == NT - 2)
            asm volatile("s_waitcnt vmcnt(0)" ::: "memory");
        __builtin_amdgcn_s_barrier();
        __builtin_amdgcn_s_setprio(1);
#pragma unroll
        for (int mf = 2; mf < 4; mf++)
#pragma unroll
            for (int nf = 3; nf < 6; nf++)
#pragma unroll
                for (int ks = 0; ks < 2; ks++)
                    acc[mf][nf] = __builtin_amdgcn_mfma_f32_16x16x32_f16(a[mf][ks], b[nf][ks], acc[mf][nf], 0, 0, 0);
        __builtin_amdgcn_s_setprio(0);
        __builtin_amdgcn_s_barrier();
    }

    // epilogue: single-pass LDS repack [128][200] -> coalesced uint4 scatter
#pragma unroll
    for (int mf = 0; mf < 4; mf++)
#pragma unroll
        for (int nf = 0; nf < 6; nf++) {
            int col = wn * 96 + nf * 16 + cb;
            float sc = ((bn + col) >> 11) == 0 ? QSCALE : 1.0f;
#pragma unroll
            for (int r = 0; r < 4; r++) {
                int row = wm * 64 + mf * 16 + hi * 4 + r;
                smem[row * 200 + col] = (_Float16)(acc[mf][nf][r] * sc);
            }
        }
    __builtin_amdgcn_s_barrier();
#pragma unroll
    for (int it = 0; it < 12; it++) {
        int c = it * 256 + tid;  // 3072 chunks = 128 rows x 24
        int row = c / 24, col8 = c - row * 24;
        int gm = bm + row;
        int gn = bn + col8 * 8;
        int tensor = gn >> 11;
        int ef = gn & 2047;
        int e = ef >> 7, f0 = ef & 127;
        uint4 v = *(const uint4*)&smem[row * 200 + col8 * 8];
        *(uint4*)(qkv + (size_t)tensor * (T_DIM * H_DIM) + (size_t)e * (T_DIM * DH) +
                  (size_t)gm * DH + f0) = v;
    }
}

// =============== out-proj: 128x64 tile, full K, fp32 out, 512 blocks = 2/CU (r10) ========
__global__ __launch_bounds__(256, 2) void oproj_kernel(const _Float16* __restrict__ A,
                                                       const _Float16* __restrict__ BT,
                                                       float* __restrict__ out) {
    const int K = 2048, NT = 32;
    __shared__ _Float16 smem[36864];  // 72KB: 3 bufs x (A 8192 | B 4096) f16

    int tid = threadIdx.x;
    int lane = tid & 63, wave = tid >> 6;
    int wm = wave >> 1, wn = wave & 1;  // 2M x 2N, wave tile 64x32
    int cb = lane & 15, hi = lane >> 4;

    int bid = blockIdx.x;
    int by = bid >> 5, bx = bid & 31;
    int bm = by * 128, bn = bx * 64;

    f32x4 acc[4][2];
#pragma unroll
    for (int m = 0; m < 4; m++)
#pragma unroll
        for (int n = 0; n < 2; n++) acc[m][n] = (f32x4){0.f, 0.f, 0.f, 0.f};

    int rp = tid >> 3, cc = tid & 7;
    int scol = ((cc ^ (rp & 7)) << 3);

    auto bufp = [&](int t) { return smem + (t % 3) * 12288; };
    auto stageA = [&](int t, int u) {
        gl_lds16(A + (size_t)(bm + u * 32 + rp) * K + (t << 6) + scol,
                 bufp(t) + u * 2048 + tid * 8);
    };
    auto stageB = [&](int t, int u) {
        gl_lds16(BT + (size_t)(bn + u * 32 + rp) * K + (t << 6) + scol,
                 bufp(t) + 8192 + u * 2048 + tid * 8);
    };

    f16x8 a[4][2], b0[2], b1[2];

    stageA(0, 0); stageA(0, 1); stageA(0, 2); stageA(0, 3); stageB(0, 0); stageB(0, 1);
    stageA(1, 0); stageA(1, 1); stageA(1, 2); stageA(1, 3); stageB(1, 0); stageB(1, 1);
    asm volatile("s_waitcnt vmcnt(6)" ::: "memory");
    __builtin_amdgcn_s_barrier();

    for (int t = 0; t < NT; t++) {
        const char* bA = (const char*)bufp(t);
        const char* bB = bA + 16384;  // 8192 f16
        // ---- ph0: read a(8) + b0(2); stage A(t+2) x4; MFMA a x b0 ----
#pragma unroll
        for (int mf = 0; mf < 4; mf++) {
            int ra = wm * 64 + mf * 16 + cb;
#pragma unroll
            for (int ks = 0; ks < 2; ks++)
                a[mf][ks] = *(const f16x8*)(bA + (ra << 7) +
                                            ((ks * 64 + hi * 16) ^ ((ra & 7) << 4)));
        }
        {
            int rb = wn * 32 + cb;
#pragma unroll
            for (int ks = 0; ks < 2; ks++)
                b0[ks] = *(const f16x8*)(bB + (rb << 7) +
                                         ((ks * 64 + hi * 16) ^ ((rb & 7) << 4)));
        }
        if (t + 2 < NT) { stageA(t + 2, 0); stageA(t + 2, 1); stageA(t + 2, 2); stageA(t + 2, 3); }
        __builtin_amdgcn_s_barrier();
        asm volatile("s_waitcnt lgkmcnt(0)" ::: "memory");
        __builtin_amdgcn_s_setprio(1);
#pragma unroll
        for (int mf = 0; mf < 4; mf++)
#pragma unroll
            for (int ks = 0; ks < 2; ks++)
                acc[mf][0] = __builtin_amdgcn_mfma_f32_16x16x32_f16(a[mf][ks], b0[ks], acc[mf][0], 0, 0, 0);
        __builtin_amdgcn_s_setprio(0);
        __builtin_amdgcn_s_barrier();

        // ---- ph1: read b1(2); stage B(t+2) x2; vmcnt; MFMA a x b1 ----
        {
            int rb = wn * 32 + 16 + cb;
#pragma unroll
            for (int ks = 0; ks < 2; ks++)
                b1[ks] = *(const f16x8*)(bB + (rb << 7) +
                                         ((ks * 64 + hi * 16) ^ ((rb & 7) << 4)));
        }
        if (t + 2 < NT) { stageB(t + 2, 0); stageB(t + 2, 1); }
        if (t < NT - 2)
            asm volatile("s_waitcnt vmcnt(6)" ::: "memory");
        else if (t == NT - 2)
            asm volatile("s_waitcnt vmcnt(0)" ::: "memory");
        __builtin_amdgcn_s_barrier();
        asm volatile("s_waitcnt lgkmcnt(0)" ::: "memory");
        __builtin_amdgcn_s_setprio(1);
#pragma unroll
        for (int mf = 0; mf < 4; mf++)
#pragma unroll
            for (int ks = 0; ks < 2; ks++)
                acc[mf][1] = __builtin_amdgcn_mfma_f32_16x16x32_f16(a[mf][ks], b1[ks], acc[mf][1], 0, 0, 0);
        __builtin_amdgcn_s_setprio(0);
        __builtin_amdgcn_s_barrier();
    }

    // epilogue: direct fp32 stores
#pragma unroll
    for (int mf = 0; mf < 4; mf++)
#pragma unroll
        for (int nf = 0; nf < 2; nf++) {
            int gn = bn + wn * 32 + nf * 16 + cb;
#pragma unroll
            for (int r = 0; r < 4; r++) {
                int gm = bm + wm * 64 + mf * 16 + hi * 4 + r;
                out[(size_t)gm * H_DIM + gn] = acc[mf][nf][r];
            }
        }
}

// ---------------- attention + (fused) Wo transpose ----------------
// Blocks [0, 656): per-(block,head) attention (round-9 code, unchanged).
// Blocks [656, 656+4096): transpose Wo fp32 -> WoT fp16 (hidden under attn slack;
// WoT complete when this kernel retires, consumed by oproj launched after).
__global__ __launch_bounds__(256) void attn_kernel(const _Float16* __restrict__ qkvb,
                                                   const float* __restrict__ bias,
                                                   const float* __restrict__ mask,
                                                   _Float16* __restrict__ aout,
                                                   const float* __restrict__ Wo,
                                                   _Float16* __restrict__ WoT) {
    __shared__ _Float16 Qs[64 * 136];
    __shared__ _Float16 Ks[64 * 136];
    __shared__ _Float16 VTs[128 * 72];
    __shared__ _Float16 Ps[64 * 72];
    __shared__ float maskv[64];

    int bid = blockIdx.x;
    int tid = threadIdx.x;

    if (bid >= NBLK * N_HEADS) {
        // ---- Wo transpose block (32x32 tile), reuses Qs as staging ----
        float* tile = (float*)Qs;  // needs 32*33*4 = 4224 B <= 17408 B
        int tb = bid - NBLK * N_HEADS;
        int tbx = (tb & 63) * 32, tby = (tb >> 6) * 32;
        int tx = tid & 31, ty = tid >> 5;  // 32 x 8
#pragma unroll
        for (int i = 0; i < 4; i++)
            tile[(ty + i * 8) * 33 + tx] = Wo[(size_t)(tby + ty + i * 8) * H_DIM + tbx + tx];
        __syncthreads();
#pragma unroll
        for (int i = 0; i < 4; i++)
            WoT[(size_t)(tbx + ty + i * 8) * H_DIM + tby + tx] =
                (_Float16)tile[tx * 33 + ty + i * 8];
        return;
    }

    int n = bid >> 4, e = bid & 15;
    int t0 = n * KBLK;
    int valid = (T_DIM - t0 < KBLK) ? (T_DIM - t0) : KBLK;

    int lane = tid & 63, wave = tid >> 6;
    const _Float16* qp = qkvb + (size_t)e * (T_DIM * DH);
    const _Float16* kp = qkvb + (size_t)(T_DIM * H_DIM) + (size_t)e * (T_DIM * DH);
    const _Float16* vp = qkvb + (size_t)2 * (T_DIM * H_DIM) + (size_t)e * (T_DIM * DH);

#pragma unroll
    for (int i = 0; i < 4; i++) {
        int c = tid + i * 256;
        int r = c >> 4, c8 = c & 15;
        uint4 z = {0u, 0u, 0u, 0u};
        uint4 vq = z, vk = z;
        if (r < valid) {
            vq = *(const uint4*)&qp[(size_t)(t0 + r) * DH + c8 * 8];
            vk = *(const uint4*)&kp[(size_t)(t0 + r) * DH + c8 * 8];
        }
        *(uint4*)&Qs[r * 136 + c8 * 8] = vq;
        *(uint4*)&Ks[r * 136 + c8 * 8] = vk;
    }
#pragma unroll
    for (int i = 0; i < 4; i++) {
        int c = tid + i * 256;
        int r = c & 63;
        int f0 = (c >> 6) * 8;
        uint4 v = {0u, 0u, 0u, 0u};
        if (r < valid) v = *(const uint4*)&vp[(size_t)(t0 + r) * DH + f0];
        _Float16 tmp[8];
        *(uint4*)tmp = v;
#pragma unroll
        for (int j = 0; j < 8; j++) VTs[(f0 + j) * 72 + r] = tmp[j];
    }
    if (tid < 64) maskv[tid] = (tid < valid) ? mask[t0 + tid] : NEGV;
    __syncthreads();

    int qr0 = wave * 16;
    int cb = lane & 15, hi = lane >> 4;

    f16x8 aq[4];
#pragma unroll
    for (int ks = 0; ks < 4; ks++)
        aq[ks] = *(const f16x8*)&Qs[(qr0 + cb) * 136 + ks * 32 + hi * 8];
    f32x4 s[4];
#pragma unroll
    for (int kt = 0; kt < 4; kt++) s[kt] = (f32x4){0.f, 0.f, 0.f, 0.f};
#pragma unroll
    for (int kt = 0; kt < 4; kt++)
#pragma unroll
        for (int ks = 0; ks < 4; ks++) {
            f16x8 bk = *(const f16x8*)&Ks[(kt * 16 + cb) * 136 + ks * 32 + hi * 8];
            s[kt] = __builtin_amdgcn_mfma_f32_16x16x32_f16(aq[ks], bk, s[kt], 0, 0, 0);
        }

#pragma unroll
    for (int r = 0; r < 4; r++) {
        int rl = qr0 + hi * 4 + r;
        int qi = t0 + rl;
        float mq = maskv[rl];
        float lg[4];
        float mx = -3.4e38f;
#pragma unroll
        for (int kt = 0; kt < 4; kt++) {
            int cl = kt * 16 + cb, ki = t0 + cl;
            float bg = (qi < T_DIM && ki < T_DIM)
                           ? bias[((size_t)e * T_DIM + qi) * T_DIM + ki] : 0.f;
            float pr = mq * maskv[cl];
            float v = s[kt][r] + bg + (pr > 0.f ? 0.f : NEGV);
            lg[kt] = v;
            mx = fmaxf(mx, v);
        }
#pragma unroll
        for (int off = 8; off; off >>= 1) mx = fmaxf(mx, __shfl_xor(mx, off));
        float sum = 0.f;
#pragma unroll
        for (int kt = 0; kt < 4; kt++) {
            float pe = __expf(lg[kt] - mx);
            lg[kt] = pe;
            sum += pe;
        }
#pragma unroll
        for (int off = 8; off; off >>= 1) sum += __shfl_xor(sum, off);
        float inv = 1.f / sum;
#pragma unroll
        for (int kt = 0; kt < 4; kt++)
            Ps[rl * 72 + kt * 16 + cb] = (_Float16)(lg[kt] * inv);
    }
    __syncthreads();

    f16x8 pa[2];
#pragma unroll
    for (int ks = 0; ks < 2; ks++)
        pa[ks] = *(const f16x8*)&Ps[(qr0 + cb) * 72 + ks * 32 + hi * 8];
#pragma unroll
    for (int ft = 0; ft < 8; ft++) {
        f32x4 o = (f32x4){0.f, 0.f, 0.f, 0.f};
#pragma unroll
        for (int ks = 0; ks < 2; ks++) {
            f16x8 bv = *(const f16x8*)&VTs[(ft * 16 + cb) * 72 + ks * 32 + hi * 8];
            o = __builtin_amdgcn_mfma_f32_16x16x32_f16(pa[ks], bv, o, 0, 0, 0);
        }
#pragma unroll
        for (int r = 0; r < 4; r++) {
            int rl = qr0 + hi * 4 + r;
            if (rl < valid)
                aout[(size_t)(t0 + rl) * H_DIM + e * DH + ft * 16 + cb] = (_Float16)o[r];
        }
    }
}

extern "C" void kernel_launch(void* const* d_in, const int* in_sizes, int n_in,
                              void* d_out, int out_size, void* d_ws, size_t ws_size,
                              hipStream_t stream) {
    const float* x    = (const float*)d_in[0];
    const float* mask = (const float*)d_in[1];
    const float* bias = (const float*)d_in[2];
    const float* Wq   = (const float*)d_in[3];
    const float* Wk   = (const float*)d_in[4];
    const float* Wv   = (const float*)d_in[5];
    const float* Wo   = (const float*)d_in[6];
    float* out = (float*)d_out;

    // ws layout (f16): xb[4M] | WT[12M] | WoT[4M] | qkv[12M] | aout[4M] = 72MB
    _Float16* xb   = (_Float16*)d_ws;
    _Float16* WT   = xb + (size_t)T_DIM * H_DIM;
    _Float16* WoT  = WT + (size_t)3 * T_DIM * H_DIM;
    _Float16* qkvb = WoT + (size_t)T_DIM * H_DIM;
    _Float16* aout = qkvb + (size_t)3 * T_DIM * H_DIM;

    // prep: Wq/Wk/Wv transpose + x convert (Wo handled inside attn kernel)
    prep_kernel<<<dim3(64, 64, 4), dim3(32, 8), 0, stream>>>(x, Wq, Wk, Wv, xb, WT);

    // QKV projection: 128x192 tiles -> 512 blocks (2/CU)
    qkv_kernel<<<512, 256, 0, stream>>>(xb, WT, qkvb);

    // attention (656 blocks) + fused Wo transpose (4096 blocks)
    attn_kernel<<<NBLK * N_HEADS + 4096, 256, 0, stream>>>(qkvb, bias, mask, aout, Wo, WoT);

    // out-proj: 128x64 tiles -> 512 blocks (2/CU), full-K fp32, direct output
    oproj_kernel<<<512, 256, 0, stream>>>(aout, WoT, out);
}